// Round 5
// baseline (15856.673 us; speedup 1.0000x reference)
//
#include <hip/hip_runtime.h>

typedef unsigned long long u64;

// ---------------- mask decode: bool[4096][64] -> attend-bitmap per window --
// Robust to u8 / int32 / float32 storage (probe: byte at t*64+63 is a real
// mask byte under u8 (ones ~62); under i32 it's a high byte of 0/1 (ones=0);
// under f32 it's the top byte of 0.0f/1.0f at col 15/31/47/63 (ones ~23).
// ones>32 -> u8 path, else 4-byte path (nonzero word <=> true for i32 AND f32).
__global__ void decode_mask_k(const unsigned char* __restrict__ mb,
                              u64* __restrict__ vbits) {
    int w = blockIdx.x, t = threadIdx.x;            // 64 threads = 1 wave
    unsigned char smp = mb[t * 64 + 63];
    int ones = __popcll(__ballot(smp != 0));
    bool u8mode = ones > 32;
    int m;
    if (u8mode) m = (mb[(size_t)w * 64 + t] != 0);
    else        m = (((const int*)mb)[(size_t)w * 64 + t] != 0);
    u64 bm = __ballot(m);                           // 1 = padded key
    if (t == 0) vbits[w] = ~bm;                     // 1 = attended key
}

// ---------------- DIAGNOSTIC: all-f32 all-VALU encoder layer ---------------
// One block per window. No MFMA, no bf16, no transposed-weight staging, no
// count-based masking. Shares NOTHING with the optimized machinery except
// the mask probe above and the problem semantics. Correctness probe only.
__global__ __launch_bounds__(256, 1) void enc_boring(
    const float* __restrict__ feat, const float* __restrict__ pos,
    const u64* __restrict__ vbits,
    const float* __restrict__ Wq, const float* __restrict__ bq,
    const float* __restrict__ Wk, const float* __restrict__ bk,
    const float* __restrict__ Wv, const float* __restrict__ bv,
    const float* __restrict__ Wo, const float* __restrict__ bo,
    const float* __restrict__ W1, const float* __restrict__ b1,
    const float* __restrict__ W2, const float* __restrict__ b2,
    const float* __restrict__ g1, const float* __restrict__ be1,
    const float* __restrict__ g2, const float* __restrict__ be2,
    float* __restrict__ out) {
    __shared__ float S[32768];               // 128 KiB -> 1 block/CU
    __shared__ float mu_s[64], rs_s[64];
    float* A  = S;                           // Q,   later ffn2-pre
    float* B  = S + 8192;                    // K,   later src
    float* C  = S + 16384;                   // V    (F1 low half)
    float* D  = S + 24576;                   // ctx  (F1 high half)
    float* F1 = S + 16384;                   // [64][256] spans C|D

    const int w = blockIdx.x, t = threadIdx.x;
    const float* fw = feat + (size_t)w * 8192;
    const float* pw = pos  + (size_t)w * 8192;
    const int s  = t >> 2;                   // this thread's row
    const int n0 = (t & 3) * 32;             // its 32-col slice

    // ---- phase 1: Q = (f+p)Wq+bq, K = (f+p)Wk+bk, V = f Wv+bv (f32) ------
    {
        const float* xr = fw + s * 128;
        const float* pr = pw + s * 128;
        for (int nn = 0; nn < 32; ++nn) {
            int n = n0 + nn;
            float aq = 0.f, ak = 0.f, av = 0.f;
            for (int k = 0; k < 128; ++k) {
                float f = xr[k];
                float x = f + pr[k];
                aq += x * Wq[k * 128 + n];
                ak += x * Wk[k * 128 + n];
                av += f * Wv[k * 128 + n];
            }
            A[s * 128 + n] = aq + bq[n];
            B[s * 128 + n] = ak + bk[n];
            C[s * 128 + n] = av + bv[n];
        }
    }
    __syncthreads();

    // ---- phase 2: attention, f32 flash, per-key bitmap mask --------------
    {
        const u64 vb = vbits[w];
        for (int pass = 0; pass < 2; ++pass) {
            int task = t + pass * 256;       // 512 (q,h) tasks
            int q = task >> 3, h = task & 7;
            const float* Qp = A + q * 128 + h * 16;
            float qr[16];
            for (int i = 0; i < 16; ++i) qr[i] = Qp[i];
            float m_ = -3e38f, l = 0.f, cx[16];
            for (int i = 0; i < 16; ++i) cx[i] = 0.f;
            for (int k = 0; k < 64; ++k) {
                if (!((vb >> k) & 1ull)) continue;   // block-uniform branch
                const float* Kp = B + k * 128 + h * 16;
                float sc_ = 0.f;
                for (int i = 0; i < 16; ++i) sc_ += qr[i] * Kp[i];
                sc_ *= 0.25f;                // 1/sqrt(DH), DH=16
                float nm  = fmaxf(m_, sc_);
                float esc = __expf(m_ - nm); // first hit: exp(-3e38) = 0
                float p   = __expf(sc_ - nm);
                l = l * esc + p;
                const float* Vp = C + k * 128 + h * 16;
                for (int i = 0; i < 16; ++i) cx[i] = cx[i] * esc + p * Vp[i];
                m_ = nm;
            }
            float inv = 1.f / l;
            float* Cp = D + q * 128 + h * 16;
            for (int i = 0; i < 16; ++i) Cp[i] = cx[i] * inv;
        }
    }
    __syncthreads();

    // ---- phase 3: tmp = feat + ctx@Wo + bo -> B; LN1 in-place ------------
    {
        const float* cr = D + s * 128;
        for (int nn = 0; nn < 32; ++nn) {
            int n = n0 + nn;
            float o = 0.f;
            for (int k = 0; k < 128; ++k) o += cr[k] * Wo[k * 128 + n];
            B[s * 128 + n] = o + bo[n] + fw[s * 128 + n];
        }
    }
    __syncthreads();
    if (t < 64) {
        const float* row = B + t * 128;
        float mu = 0.f;
        for (int k = 0; k < 128; ++k) mu += row[k];
        mu *= 0.0078125f;
        float var = 0.f;
        for (int k = 0; k < 128; ++k) { float d = row[k] - mu; var += d * d; }
        var *= 0.0078125f;
        mu_s[t] = mu; rs_s[t] = rsqrtf(var + 1e-5f);
    }
    __syncthreads();
    for (int nn = 0; nn < 32; ++nn) {
        int n = n0 + nn;
        B[s * 128 + n] = (B[s * 128 + n] - mu_s[s]) * rs_s[s] * g1[n] + be1[n];
    }
    __syncthreads();

    // ---- phase 4: F1 = relu(src@W1 + b1) ---------------------------------
    {
        const int c0 = (t & 3) * 64;
        const float* sr = B + s * 128;
        for (int cc = 0; cc < 64; ++cc) {
            int c = c0 + cc;
            float a = 0.f;
            for (int k = 0; k < 128; ++k) a += sr[k] * W1[k * 256 + c];
            F1[s * 256 + c] = fmaxf(a + b1[c], 0.f);
        }
    }
    __syncthreads();

    // ---- phase 5: ffn2 + residual(src) -> A; LN2 -> out ------------------
    {
        const float* fr = F1 + s * 256;
        for (int nn = 0; nn < 32; ++nn) {
            int n = n0 + nn;
            float o = 0.f;
            for (int k = 0; k < 256; ++k) o += fr[k] * W2[k * 128 + n];
            A[s * 128 + n] = o + b2[n] + B[s * 128 + n];
        }
    }
    __syncthreads();
    if (t < 64) {
        const float* row = A + t * 128;
        float mu = 0.f;
        for (int k = 0; k < 128; ++k) mu += row[k];
        mu *= 0.0078125f;
        float var = 0.f;
        for (int k = 0; k < 128; ++k) { float d = row[k] - mu; var += d * d; }
        var *= 0.0078125f;
        mu_s[t] = mu; rs_s[t] = rsqrtf(var + 1e-5f);
    }
    __syncthreads();
    float* ow = out + (size_t)w * 8192;
    for (int nn = 0; nn < 32; ++nn) {
        int n = n0 + nn;
        ow[s * 128 + n] = (A[s * 128 + n] - mu_s[s]) * rs_s[s] * g2[n] + be2[n];
    }
}

extern "C" void kernel_launch(void* const* d_in, const int* in_sizes, int n_in,
                              void* d_out, int out_size, void* d_ws, size_t ws_size,
                              hipStream_t stream) {
    (void)in_sizes; (void)n_in; (void)out_size; (void)ws_size;
    const float* feat = (const float*)d_in[0];
    const float* pos  = (const float*)d_in[1];
    const unsigned char* mask = (const unsigned char*)d_in[2];
    const float* Wq = (const float*)d_in[3];  const float* bq = (const float*)d_in[4];
    const float* Wk = (const float*)d_in[5];  const float* bk = (const float*)d_in[6];
    const float* Wv = (const float*)d_in[7];  const float* bv = (const float*)d_in[8];
    const float* Wo = (const float*)d_in[9];  const float* bo = (const float*)d_in[10];
    const float* W1 = (const float*)d_in[11]; const float* b1 = (const float*)d_in[12];
    const float* W2 = (const float*)d_in[13]; const float* b2 = (const float*)d_in[14];
    const float* g1 = (const float*)d_in[15]; const float* be1 = (const float*)d_in[16];
    const float* g2 = (const float*)d_in[17]; const float* be2 = (const float*)d_in[18];

    u64* vbits = (u64*)d_ws;

    decode_mask_k<<<4096, 64, 0, stream>>>(mask, vbits);
    enc_boring<<<4096, 256, 0, stream>>>(feat, pos, vbits,
                                         Wq, bq, Wk, bk, Wv, bv, Wo, bo,
                                         W1, b1, W2, b2, g1, be1, g2, be2,
                                         (float*)d_out);
}

// Round 6
// 808.535 us; speedup vs baseline: 19.6116x; 19.6116x over previous
//
#include <hip/hip_runtime.h>

typedef __attribute__((ext_vector_type(8))) short bf16x8;
typedef __attribute__((ext_vector_type(4))) float f32x4;
typedef unsigned short u16;
typedef unsigned int u32;

#define MFMA16(a, b, c) __builtin_amdgcn_mfma_f32_16x16x32_bf16((a), (b), (c), 0, 0, 0)

__device__ __forceinline__ u16 f2bf(float f) {
    union { float f; u32 u; } c; c.f = f;
    u32 r = c.u + 0x7fffu + ((c.u >> 16) & 1u);   // round-to-nearest-even
    return (u16)(r >> 16);
}
__device__ __forceinline__ float bf2f(u32 bits16) {
    union { u32 u; float f; } c; c.u = bits16 << 16;
    return c.f;
}

// ---------------- mask decode: bool[4096][64] -> valid count per window ----
// Ballot/probe logic validated by round-5 pass. Uses 16 KB of d_ws (safe:
// round 5 proved ws_size >= 32 KB by using 32 KB successfully).
__global__ void decode_mask_k(const unsigned char* __restrict__ mb,
                              int* __restrict__ valid) {
    int w = blockIdx.x, t = threadIdx.x;            // 64 threads = 1 wave
    unsigned char smp = mb[t * 64 + 63];
    int ones = __popcll(__ballot(smp != 0));
    bool u8mode = ones > 32;
    int m;
    if (u8mode) m = (mb[(size_t)w * 64 + t] != 0);
    else        m = (((const int*)mb)[(size_t)w * 64 + t] != 0);
    unsigned long long bm = __ballot(m);
    if (t == 0) valid[w] = 64 - __popcll(bm);       // attended-prefix length
}

// ---- stage one 128x128 transposed bf16 weight panel into LDS --------------
// dest[n][k] (stride 136) = W[(k0+k)*ld + n0+n]. Global reads coalesced
// (consecutive t -> consecutive n). NO d_ws involved (R1-R4 bug: wT staging
// overflowed ws_size).
__device__ __forceinline__ void stage_w(const float* __restrict__ W, int ld,
                                        int n0, int k0, u16* __restrict__ sW,
                                        int t) {
#pragma unroll 8
    for (int i = 0; i < 64; ++i) {
        int e = i * 256 + t;                        // 16384 elems total
        int n = e & 127, k = e >> 7;
        sW[n * 136 + k] = f2bf(W[(size_t)(k0 + k) * ld + n0 + n]);
    }
}

// MFMA 16x16x32 bf16 (layouts pinned by learn_hip m89/m91/m97 refchecks):
// A-frag row=lane&15, k=(lane>>4)*8+j. B-frag col=lane&15, same k map.
// C/D: col=lane&15, row=(lane>>4)*4+reg.
__device__ __forceinline__ void row_ln(const f32x4 v[8], float mu[4], float rs[4]) {
#pragma unroll
    for (int r = 0; r < 4; ++r) {
        float s = 0.f;
#pragma unroll
        for (int nt = 0; nt < 8; ++nt) s += v[nt][r];
        s += __shfl_xor(s, 1); s += __shfl_xor(s, 2);
        s += __shfl_xor(s, 4); s += __shfl_xor(s, 8);
        float m_ = s * 0.0078125f;
        float q = 0.f;
#pragma unroll
        for (int nt = 0; nt < 8; ++nt) { float d = v[nt][r] - m_; q += d * d; }
        q += __shfl_xor(q, 1); q += __shfl_xor(q, 2);
        q += __shfl_xor(q, 4); q += __shfl_xor(q, 8);
        mu[r] = m_;
        rs[r] = rsqrtf(q * 0.0078125f + 1e-5f);
    }
}

__global__ __launch_bounds__(256) void enc_main(
    const float* __restrict__ feat, const float* __restrict__ pos,
    const int* __restrict__ valid,
    const float* __restrict__ Wq, const float* __restrict__ bq,
    const float* __restrict__ Wk, const float* __restrict__ bk,
    const float* __restrict__ Wv, const float* __restrict__ bv,
    const float* __restrict__ Wo, const float* __restrict__ bo,
    const float* __restrict__ W1, const float* __restrict__ b1,
    const float* __restrict__ W2, const float* __restrict__ b2,
    const float* __restrict__ g1, const float* __restrict__ be1,
    const float* __restrict__ g2, const float* __restrict__ be2,
    float* __restrict__ out) {
    // LDS 104448 B -> 1 block/CU this round
    __shared__ __align__(16) char smem[104448];
    u16* sQ   = (u16*)smem;                  // [64][136]  Q, later src(bf16)
    u16* sK   = (u16*)(smem + 17408);        // [64][136]
    u16* sV   = (u16*)(smem + 34816);        // [64][136]
    u16* sCtx = (u16*)(smem + 52224);        // [64][136]
    u16* sW   = (u16*)(smem + 69632);        // [128][136] staged weight panel
    u16* sF1  = (u16*)(smem + 17408);        // [64][264]  overlays sK+sV

    const int w    = blockIdx.x;
    const int tid  = threadIdx.x;
    const int lane = tid & 63;
    const int lr   = lane & 15;
    const int lk   = lane >> 4;
    const int m0   = (tid >> 6) * 16;        // wave's row base

    const float* fw = feat + (size_t)w * 8192;
    const float* pw = pos  + (size_t)w * 8192;
    const int vld = valid[w];

    // ---- A fragments straight from global: X = feat+pos, Fv = feat --------
    bf16x8 aX[4], aFv[4];
#pragma unroll
    for (int ks = 0; ks < 4; ++ks) {
        const float* fp = fw + (m0 + lr) * 128 + ks * 32 + lk * 8;
        const float* pp = pw + (m0 + lr) * 128 + ks * 32 + lk * 8;
        f32x4 f0 = *(const f32x4*)fp;
        f32x4 f1 = *(const f32x4*)(fp + 4);
        f32x4 p0 = *(const f32x4*)pp;
        f32x4 p1 = *(const f32x4*)(pp + 4);
        bf16x8 x, fv;
#pragma unroll
        for (int j = 0; j < 4; ++j) {
            fv[j]     = (short)f2bf(f0[j]);
            fv[j + 4] = (short)f2bf(f1[j]);
            x[j]      = (short)f2bf(f0[j] + p0[j]);
            x[j + 4]  = (short)f2bf(f1[j] + p1[j]);
        }
        aX[ks] = x; aFv[ks] = fv;
    }

    // ---- Q = X@Wq + bq ------------------------------------------------------
    stage_w(Wq, 128, 0, 0, sW, tid);
    __syncthreads();
    {
        f32x4 acc[8] = {};
#pragma unroll
        for (int ks = 0; ks < 4; ++ks)
#pragma unroll
            for (int nt = 0; nt < 8; ++nt) {
                bf16x8 b = *(const bf16x8*)(sW + (nt * 16 + lr) * 136 + ks * 32 + lk * 8);
                acc[nt] = MFMA16(aX[ks], b, acc[nt]);
            }
#pragma unroll
        for (int nt = 0; nt < 8; ++nt) {
            int col = nt * 16 + lr; float bb = bq[col];
#pragma unroll
            for (int r = 0; r < 4; ++r)
                sQ[(m0 + lk * 4 + r) * 136 + col] = f2bf(acc[nt][r] + bb);
        }
    }
    __syncthreads();
    // ---- K = X@Wk + bk ------------------------------------------------------
    stage_w(Wk, 128, 0, 0, sW, tid);
    __syncthreads();
    {
        f32x4 acc[8] = {};
#pragma unroll
        for (int ks = 0; ks < 4; ++ks)
#pragma unroll
            for (int nt = 0; nt < 8; ++nt) {
                bf16x8 b = *(const bf16x8*)(sW + (nt * 16 + lr) * 136 + ks * 32 + lk * 8);
                acc[nt] = MFMA16(aX[ks], b, acc[nt]);
            }
#pragma unroll
        for (int nt = 0; nt < 8; ++nt) {
            int col = nt * 16 + lr; float bb = bk[col];
#pragma unroll
            for (int r = 0; r < 4; ++r)
                sK[(m0 + lk * 4 + r) * 136 + col] = f2bf(acc[nt][r] + bb);
        }
    }
    __syncthreads();
    // ---- V = feat@Wv + bv ---------------------------------------------------
    stage_w(Wv, 128, 0, 0, sW, tid);
    __syncthreads();
    {
        f32x4 acc[8] = {};
#pragma unroll
        for (int ks = 0; ks < 4; ++ks)
#pragma unroll
            for (int nt = 0; nt < 8; ++nt) {
                bf16x8 b = *(const bf16x8*)(sW + (nt * 16 + lr) * 136 + ks * 32 + lk * 8);
                acc[nt] = MFMA16(aFv[ks], b, acc[nt]);
            }
#pragma unroll
        for (int nt = 0; nt < 8; ++nt) {
            int col = nt * 16 + lr; float bb = bv[col];
#pragma unroll
            for (int r = 0; r < 4; ++r)
                sV[(m0 + lk * 4 + r) * 136 + col] = f2bf(acc[nt][r] + bb);
        }
    }
    __syncthreads();

    // ---- attention (R5-validated VALU flash) ∥ stage Wo --------------------
    stage_w(Wo, 128, 0, 0, sW, tid);         // sW free; overlaps attention
#pragma unroll 1
    for (int pass = 0; pass < 2; ++pass) {
        int task = tid + pass * 256;         // 512 (q,h) tasks
        int q = task >> 3, h = task & 7;
        const u16* Qp = sQ + q * 136 + h * 16;
        bf16x8 q0 = *(const bf16x8*)Qp;
        bf16x8 q1 = *(const bf16x8*)(Qp + 8);
        float Qr[16];
#pragma unroll
        for (int i = 0; i < 8; ++i) {
            Qr[i]     = bf2f((u16)q0[i]);
            Qr[8 + i] = bf2f((u16)q1[i]);
        }
        float m_ = -3e38f, l = 0.f, cx[16];
#pragma unroll
        for (int i = 0; i < 16; ++i) cx[i] = 0.f;
        for (int k = 0; k < vld; ++k) {
            const u16* Kp = sK + k * 136 + h * 16;
            bf16x8 k0 = *(const bf16x8*)Kp;
            bf16x8 k1 = *(const bf16x8*)(Kp + 8);
            float s = 0.f;
#pragma unroll
            for (int i = 0; i < 8; ++i)
                s += Qr[i] * bf2f((u16)k0[i]) + Qr[8 + i] * bf2f((u16)k1[i]);
            s *= 0.25f;                      // 1/sqrt(DH), DH=16
            float nm  = fmaxf(m_, s);
            float esc = __expf(m_ - nm);     // first iter: exp(-inf) = 0
            float p   = __expf(s - nm);
            l = l * esc + p;
            const u16* Vp = sV + k * 136 + h * 16;
            bf16x8 v0 = *(const bf16x8*)Vp;
            bf16x8 v1 = *(const bf16x8*)(Vp + 8);
#pragma unroll
            for (int i = 0; i < 8; ++i) {
                cx[i]     = cx[i]     * esc + p * bf2f((u16)v0[i]);
                cx[8 + i] = cx[8 + i] * esc + p * bf2f((u16)v1[i]);
            }
            m_ = nm;
        }
        float inv = 1.f / l;
        bf16x8 r0, r1;
#pragma unroll
        for (int i = 0; i < 8; ++i) {
            r0[i] = (short)f2bf(cx[i] * inv);
            r1[i] = (short)f2bf(cx[8 + i] * inv);
        }
        u16* Cp = sCtx + q * 136 + h * 16;
        *(bf16x8*)Cp = r0;
        *(bf16x8*)(Cp + 8) = r1;
    }
    __syncthreads();   // ctx + staged Wo both visible

    // ---- O-projection + residual(feat) + LN1 -------------------------------
    f32x4 v8[8];
    {
        bf16x8 aC[4];
#pragma unroll
        for (int ks = 0; ks < 4; ++ks)
            aC[ks] = *(const bf16x8*)(sCtx + (m0 + lr) * 136 + ks * 32 + lk * 8);
        f32x4 acc[8] = {};
#pragma unroll
        for (int ks = 0; ks < 4; ++ks)
#pragma unroll
            for (int nt = 0; nt < 8; ++nt) {
                bf16x8 b = *(const bf16x8*)(sW + (nt * 16 + lr) * 136 + ks * 32 + lk * 8);
                acc[nt] = MFMA16(aC[ks], b, acc[nt]);
            }
#pragma unroll
        for (int nt = 0; nt < 8; ++nt) {
            int col = nt * 16 + lr; float bb = bo[col];
#pragma unroll
            for (int r = 0; r < 4; ++r)
                v8[nt][r] = acc[nt][r] + bb + fw[(m0 + lk * 4 + r) * 128 + col];
        }
    }
    float mu[4], rs[4];
    row_ln(v8, mu, rs);
    f32x4 srcv[8];                           // f32 src kept for FFN residual
#pragma unroll
    for (int nt = 0; nt < 8; ++nt) {
        int col = nt * 16 + lr;
        float gg = g1[col], bb = be1[col];
#pragma unroll
        for (int r = 0; r < 4; ++r) {
            float sv = (v8[nt][r] - mu[r]) * rs[r] * gg + bb;
            srcv[nt][r] = sv;
            sQ[(m0 + lk * 4 + r) * 136 + col] = f2bf(sv);
        }
    }
    __syncthreads();

    // ---- FFN1: relu(src@W1 + b1) -> sF1, two 128-col panels ----------------
    bf16x8 aS[4];
#pragma unroll
    for (int ks = 0; ks < 4; ++ks)
        aS[ks] = *(const bf16x8*)(sQ + (m0 + lr) * 136 + ks * 32 + lk * 8);
#pragma unroll 1
    for (int pnl = 0; pnl < 2; ++pnl) {
        stage_w(W1, 256, pnl * 128, 0, sW, tid);
        __syncthreads();
        f32x4 f1a[8] = {};
#pragma unroll
        for (int ks = 0; ks < 4; ++ks)
#pragma unroll
            for (int nt = 0; nt < 8; ++nt) {
                bf16x8 b = *(const bf16x8*)(sW + (nt * 16 + lr) * 136 + ks * 32 + lk * 8);
                f1a[nt] = MFMA16(aS[ks], b, f1a[nt]);
            }
#pragma unroll
        for (int nt = 0; nt < 8; ++nt) {
            int col = pnl * 128 + nt * 16 + lr; float bb = b1[col];
#pragma unroll
            for (int r = 0; r < 4; ++r)
                sF1[(m0 + lk * 4 + r) * 264 + col] = f2bf(fmaxf(f1a[nt][r] + bb, 0.f));
        }
        __syncthreads();
    }

    // ---- FFN2 (two 128-k panels) + residual(src) + LN2 -> out ---------------
    f32x4 oa[8] = {};
#pragma unroll 1
    for (int pnl = 0; pnl < 2; ++pnl) {
        stage_w(W2, 128, 0, pnl * 128, sW, tid);
        __syncthreads();
#pragma unroll
        for (int ks = 0; ks < 4; ++ks) {
            bf16x8 aF = *(const bf16x8*)(sF1 + (m0 + lr) * 264 + pnl * 128 + ks * 32 + lk * 8);
#pragma unroll
            for (int nt = 0; nt < 8; ++nt) {
                bf16x8 b = *(const bf16x8*)(sW + (nt * 16 + lr) * 136 + ks * 32 + lk * 8);
                oa[nt] = MFMA16(aF, b, oa[nt]);
            }
        }
        __syncthreads();
    }
#pragma unroll
    for (int nt = 0; nt < 8; ++nt) {
        int col = nt * 16 + lr; float bb = b2[col];
#pragma unroll
        for (int r = 0; r < 4; ++r)
            v8[nt][r] = oa[nt][r] + bb + srcv[nt][r];
    }
    row_ln(v8, mu, rs);
    float* ow = out + (size_t)w * 8192;
#pragma unroll
    for (int nt = 0; nt < 8; ++nt) {
        int col = nt * 16 + lr;
        float gg = g2[col], bb = be2[col];
#pragma unroll
        for (int r = 0; r < 4; ++r)
            ow[(m0 + lk * 4 + r) * 128 + col] = (v8[nt][r] - mu[r]) * rs[r] * gg + bb;
    }
}

extern "C" void kernel_launch(void* const* d_in, const int* in_sizes, int n_in,
                              void* d_out, int out_size, void* d_ws, size_t ws_size,
                              hipStream_t stream) {
    (void)in_sizes; (void)n_in; (void)out_size; (void)ws_size;
    const float* feat = (const float*)d_in[0];
    const float* pos  = (const float*)d_in[1];
    const unsigned char* mask = (const unsigned char*)d_in[2];
    const float* Wq = (const float*)d_in[3];  const float* bq = (const float*)d_in[4];
    const float* Wk = (const float*)d_in[5];  const float* bk = (const float*)d_in[6];
    const float* Wv = (const float*)d_in[7];  const float* bv = (const float*)d_in[8];
    const float* Wo = (const float*)d_in[9];  const float* bo = (const float*)d_in[10];
    const float* W1 = (const float*)d_in[11]; const float* b1 = (const float*)d_in[12];
    const float* W2 = (const float*)d_in[13]; const float* b2 = (const float*)d_in[14];
    const float* g1 = (const float*)d_in[15]; const float* be1 = (const float*)d_in[16];
    const float* g2 = (const float*)d_in[17]; const float* be2 = (const float*)d_in[18];

    int* valid = (int*)d_ws;                 // 16 KB only (ws_size-safe)

    decode_mask_k<<<4096, 64, 0, stream>>>(mask, valid);
    enc_main<<<4096, 256, 0, stream>>>(feat, pos, valid,
                                       Wq, bq, Wk, bk, Wv, bv, Wo, bo,
                                       W1, b1, W2, b2, g1, be1, g2, be2,
                                       (float*)d_out);
}

// Round 7
// 533.311 us; speedup vs baseline: 29.7325x; 1.5161x over previous
//
#include <hip/hip_runtime.h>

typedef __attribute__((ext_vector_type(8))) short bf16x8;
typedef __attribute__((ext_vector_type(4))) float f32x4;
typedef unsigned short u16;
typedef unsigned int u32;

#define MFMA16(a, b, c) __builtin_amdgcn_mfma_f32_16x16x32_bf16((a), (b), (c), 0, 0, 0)
#define CFENCE() asm volatile("" ::: "memory")

__device__ __forceinline__ u16 f2bf(float f) {
    union { float f; u32 u; } c; c.f = f;
    u32 r = c.u + 0x7fffu + ((c.u >> 16) & 1u);   // RNE
    return (u16)(r >> 16);
}

// pack 8 f32 -> bf16x8 via HW v_cvt_pk_bf16_f32 (RNE)
__device__ __forceinline__ bf16x8 pack8(f32x4 a, f32x4 b) {
    union { u32 w[4]; bf16x8 v; } r;
    asm("v_cvt_pk_bf16_f32 %0, %1, %2" : "=v"(r.w[0]) : "v"(a[0]), "v"(a[1]));
    asm("v_cvt_pk_bf16_f32 %0, %1, %2" : "=v"(r.w[1]) : "v"(a[2]), "v"(a[3]));
    asm("v_cvt_pk_bf16_f32 %0, %1, %2" : "=v"(r.w[2]) : "v"(b[0]), "v"(b[1]));
    asm("v_cvt_pk_bf16_f32 %0, %1, %2" : "=v"(r.w[3]) : "v"(b[2]), "v"(b[3]));
    return r.v;
}

// stage 128x128 transposed bf16 panel: sW[n][k] (stride 136) = W[k0+k][n0+n].
// k-quad per thread: 4 coalesced global rows, 2 cvt_pk, one ds_write_b64.
__device__ __forceinline__ void stage_w(const float* __restrict__ W, int ld,
                                        int n0, int k0, u16* __restrict__ sW,
                                        int t) {
#pragma unroll 4
    for (int i = 0; i < 16; ++i) {
        int e = i * 256 + t;                      // 4096 quads
        int n = e & 127, kq = e >> 7;             // kq 0..31
        const float* src = W + (size_t)(k0 + kq * 4) * ld + n0 + n;
        float a = src[0], b = src[ld], c = src[2 * ld], d = src[3 * ld];
        u32 lo, hi;
        asm("v_cvt_pk_bf16_f32 %0, %1, %2" : "=v"(lo) : "v"(a), "v"(b));
        asm("v_cvt_pk_bf16_f32 %0, %1, %2" : "=v"(hi) : "v"(c), "v"(d));
        uint2 pk; pk.x = lo; pk.y = hi;
        *(uint2*)(sW + (size_t)n * 136 + kq * 4) = pk;   // 8B aligned
    }
}

// MFMA 16x16x32 bf16 (pinned: learn_hip m89/m91/m97): A row=lane&15,
// k=(lane>>4)*8+j; B col=lane&15, same k map; C/D col=lane&15, row=(lane>>4)*4+r.
__device__ __forceinline__ void row_ln(const f32x4 v[8], float mu[4], float rs[4]) {
#pragma unroll
    for (int r = 0; r < 4; ++r) {
        float s = 0.f;
#pragma unroll
        for (int nt = 0; nt < 8; ++nt) s += v[nt][r];
        s += __shfl_xor(s, 1); s += __shfl_xor(s, 2);
        s += __shfl_xor(s, 4); s += __shfl_xor(s, 8);
        float m_ = s * 0.0078125f;
        float q = 0.f;
#pragma unroll
        for (int nt = 0; nt < 8; ++nt) { float d = v[nt][r] - m_; q += d * d; }
        q += __shfl_xor(q, 1); q += __shfl_xor(q, 2);
        q += __shfl_xor(q, 4); q += __shfl_xor(q, 8);
        mu[r] = m_;
        rs[r] = rsqrtf(q * 0.0078125f + 1e-5f);
    }
}

__global__ __launch_bounds__(256) void enc_main(
    const float* __restrict__ feat, const float* __restrict__ pos,
    const unsigned char* __restrict__ maskb,
    const float* __restrict__ Wq, const float* __restrict__ bq,
    const float* __restrict__ Wk, const float* __restrict__ bk,
    const float* __restrict__ Wv, const float* __restrict__ bv,
    const float* __restrict__ Wo, const float* __restrict__ bo,
    const float* __restrict__ W1, const float* __restrict__ b1,
    const float* __restrict__ W2, const float* __restrict__ b2,
    const float* __restrict__ g1, const float* __restrict__ be1,
    const float* __restrict__ g2, const float* __restrict__ be2,
    float* __restrict__ out) {
    // LDS 132096 B -> 1 block/CU
    __shared__ __align__(16) char smem[132096];
    u16* sQ    = (u16*)smem;                 // [64][136]  Q -> ctx -> src
    u16* sK    = (u16*)(smem + 17408);       // [64][136]
    u16* sVt   = (u16*)(smem + 34816);       // [128][72]  V^T [d][seq]
    u16* sAttn = (u16*)(smem + 53248);       // [64][72]
    u16* sW0   = (u16*)(smem + 62464);       // [128][136] weight panel A
    u16* sW1   = (u16*)(smem + 97280);       // [128][136] weight panel B
    u16* sF1   = (u16*)(smem + 17408);       // [64][264]  overlays sK+sVt

    const int w    = blockIdx.x;
    const int tid  = threadIdx.x;
    const int lane = tid & 63;
    const int lr   = lane & 15;
    const int lk   = lane >> 4;
    const int m0   = (tid >> 6) * 16;

    const float* fw = feat + (size_t)w * 8192;
    const float* pw = pos  + (size_t)w * 8192;

    // ---- mask decode inline (probe logic validated R5/R6) ------------------
    int vld;
    {
        unsigned char smp = maskb[lane * 64 + 63];
        int ones = __popcll(__ballot(smp != 0));
        int m = (ones > 32) ? (maskb[(size_t)w * 64 + lane] != 0)
                            : (((const int*)maskb)[(size_t)w * 64 + lane] != 0);
        vld = 64 - __popcll(__ballot(m));
    }

    // ---- A fragments from global: X = feat+pos, Fv = feat ------------------
    bf16x8 aX[4], aFv[4];
#pragma unroll
    for (int ks = 0; ks < 4; ++ks) {
        const float* fp = fw + (m0 + lr) * 128 + ks * 32 + lk * 8;
        const float* pp = pw + (m0 + lr) * 128 + ks * 32 + lk * 8;
        f32x4 f0 = *(const f32x4*)fp;
        f32x4 f1 = *(const f32x4*)(fp + 4);
        f32x4 p0 = *(const f32x4*)pp;
        f32x4 p1 = *(const f32x4*)(pp + 4);
        aFv[ks] = pack8(f0, f1);
        aX[ks]  = pack8(f0 + p0, f1 + p1);
    }

    stage_w(Wq, 128, 0, 0, sW0, tid);
    __syncthreads();                                          // B1: Wq ready

    // ---- Q = X@Wq + bq (stage Wk overlapped) -------------------------------
    stage_w(Wk, 128, 0, 0, sW1, tid);
    {
        f32x4 acc[8] = {};
#pragma unroll
        for (int ks = 0; ks < 4; ++ks)
#pragma unroll
            for (int nt = 0; nt < 8; ++nt) {
                bf16x8 b = *(const bf16x8*)(sW0 + (nt * 16 + lr) * 136 + ks * 32 + lk * 8);
                acc[nt] = MFMA16(aX[ks], b, acc[nt]);
            }
#pragma unroll
        for (int nt = 0; nt < 8; ++nt) {
            int col = nt * 16 + lr; float bb = bq[col];
#pragma unroll
            for (int r = 0; r < 4; ++r)
                sQ[(m0 + lk * 4 + r) * 136 + col] = f2bf(acc[nt][r] + bb);
        }
    }
    __syncthreads();                                          // B2: Wk, Q ready

    // ---- K = X@Wk + bk (stage Wv overlapped) -------------------------------
    stage_w(Wv, 128, 0, 0, sW0, tid);
    {
        f32x4 acc[8] = {};
#pragma unroll
        for (int ks = 0; ks < 4; ++ks)
#pragma unroll
            for (int nt = 0; nt < 8; ++nt) {
                bf16x8 b = *(const bf16x8*)(sW1 + (nt * 16 + lr) * 136 + ks * 32 + lk * 8);
                acc[nt] = MFMA16(aX[ks], b, acc[nt]);
            }
#pragma unroll
        for (int nt = 0; nt < 8; ++nt) {
            int col = nt * 16 + lr; float bb = bk[col];
#pragma unroll
            for (int r = 0; r < 4; ++r)
                sK[(m0 + lk * 4 + r) * 136 + col] = f2bf(acc[nt][r] + bb);
        }
    }
    __syncthreads();                                          // B3: Wv, K ready

    // ---- V = feat@Wv + bv -> sVt[d][seq] (stage Wo overlapped) -------------
    stage_w(Wo, 128, 0, 0, sW1, tid);
    {
        f32x4 acc[8] = {};
#pragma unroll
        for (int ks = 0; ks < 4; ++ks)
#pragma unroll
            for (int nt = 0; nt < 8; ++nt) {
                bf16x8 b = *(const bf16x8*)(sW0 + (nt * 16 + lr) * 136 + ks * 32 + lk * 8);
                acc[nt] = MFMA16(aFv[ks], b, acc[nt]);
            }
#pragma unroll
        for (int nt = 0; nt < 8; ++nt) {
            int dcol = nt * 16 + lr; float bb = bv[dcol];
            u32 lo, hi;
            float e0 = acc[nt][0] + bb, e1 = acc[nt][1] + bb;
            float e2 = acc[nt][2] + bb, e3 = acc[nt][3] + bb;
            asm("v_cvt_pk_bf16_f32 %0, %1, %2" : "=v"(lo) : "v"(e0), "v"(e1));
            asm("v_cvt_pk_bf16_f32 %0, %1, %2" : "=v"(hi) : "v"(e2), "v"(e3));
            uint2 pk; pk.x = lo; pk.y = hi;
            *(uint2*)(sVt + dcol * 72 + m0 + lk * 4) = pk;    // 4 contig seq
        }
    }
    __syncthreads();                                          // B4: Wo, K, Vt ready

    // ---- MFMA attention (wave-local; stage W1 panel0 overlapped) -----------
    // dup trick: both 16-wide K-halves carry head-h data (offset (lk&1)*8),
    // so D = 2*S_h and scale = 0.25/2 = 0.125. Branchless, layout-safe
    // (A and B share the same k-slot map).
    stage_w(W1, 256, 0, 0, sW0, tid);
    const int dup = (lk & 1) * 8;
#pragma unroll 1
    for (int h = 0; h < 8; ++h) {
        bf16x8 aQ = *(const bf16x8*)(sQ + (m0 + lr) * 136 + h * 16 + dup);
        f32x4 sc[4];
#pragma unroll
        for (int nt = 0; nt < 4; ++nt) {
            bf16x8 bK = *(const bf16x8*)(sK + (nt * 16 + lr) * 136 + h * 16 + dup);
            f32x4 zz = {0.f, 0.f, 0.f, 0.f};
            sc[nt] = MFMA16(aQ, bK, zz);
        }
#pragma unroll
        for (int nt = 0; nt < 4; ++nt) {
            bool msk = (nt * 16 + lr) >= vld;
#pragma unroll
            for (int r = 0; r < 4; ++r) {
                float v0 = sc[nt][r] * 0.125f;
                sc[nt][r] = msk ? -1e9f : v0;
            }
        }
        float mx[4], sm[4];
#pragma unroll
        for (int r = 0; r < 4; ++r) {
            float m_ = fmaxf(fmaxf(sc[0][r], sc[1][r]), fmaxf(sc[2][r], sc[3][r]));
            m_ = fmaxf(m_, __shfl_xor(m_, 1));
            m_ = fmaxf(m_, __shfl_xor(m_, 2));
            m_ = fmaxf(m_, __shfl_xor(m_, 4));
            m_ = fmaxf(m_, __shfl_xor(m_, 8));
            mx[r] = m_; sm[r] = 0.f;
        }
#pragma unroll
        for (int nt = 0; nt < 4; ++nt)
#pragma unroll
            for (int r = 0; r < 4; ++r) {
                float e = __expf(sc[nt][r] - mx[r]);
                sc[nt][r] = e; sm[r] += e;
            }
#pragma unroll
        for (int r = 0; r < 4; ++r) {
            float s_ = sm[r];
            s_ += __shfl_xor(s_, 1); s_ += __shfl_xor(s_, 2);
            s_ += __shfl_xor(s_, 4); s_ += __shfl_xor(s_, 8);
            sm[r] = 1.f / s_;
        }
#pragma unroll
        for (int nt = 0; nt < 4; ++nt)
#pragma unroll
            for (int r = 0; r < 4; ++r)
                sAttn[(m0 + lk * 4 + r) * 72 + nt * 16 + lr] = f2bf(sc[nt][r] * sm[r]);
        CFENCE();   // P stores -> aP vector loads (wave-local)
        f32x4 cc = {0.f, 0.f, 0.f, 0.f};
#pragma unroll
        for (int ks = 0; ks < 2; ++ks) {
            bf16x8 aP = *(const bf16x8*)(sAttn + (m0 + lr) * 72 + ks * 32 + lk * 8);
            bf16x8 bV = *(const bf16x8*)(sVt + (h * 16 + lr) * 72 + ks * 32 + lk * 8);
            cc = MFMA16(aP, bV, cc);
        }
        // ctx in-place into sQ (head-h Q cols already consumed; wave-local)
#pragma unroll
        for (int r = 0; r < 4; ++r)
            sQ[(m0 + lk * 4 + r) * 136 + h * 16 + lr] = f2bf(cc[r]);
    }
    CFENCE();   // ctx stores -> aC vector loads (wave-local)

    // ---- O-projection + residual(feat) + LN1 (Wo in sW1) -------------------
    f32x4 v8[8];
    {
        bf16x8 aC[4];
#pragma unroll
        for (int ks = 0; ks < 4; ++ks)
            aC[ks] = *(const bf16x8*)(sQ + (m0 + lr) * 136 + ks * 32 + lk * 8);
        f32x4 acc[8] = {};
#pragma unroll
        for (int ks = 0; ks < 4; ++ks)
#pragma unroll
            for (int nt = 0; nt < 8; ++nt) {
                bf16x8 b = *(const bf16x8*)(sW1 + (nt * 16 + lr) * 136 + ks * 32 + lk * 8);
                acc[nt] = MFMA16(aC[ks], b, acc[nt]);
            }
#pragma unroll
        for (int nt = 0; nt < 8; ++nt) {
            int col = nt * 16 + lr; float bb = bo[col];
#pragma unroll
            for (int r = 0; r < 4; ++r)
                v8[nt][r] = acc[nt][r] + bb + fw[(m0 + lk * 4 + r) * 128 + col];
        }
    }
    float mu[4], rs[4];
    row_ln(v8, mu, rs);
    f32x4 srcv[8];
#pragma unroll
    for (int nt = 0; nt < 8; ++nt) {
        int col = nt * 16 + lr;
        float gg = g1[col], bb = be1[col];
#pragma unroll
        for (int r = 0; r < 4; ++r) {
            float sv = (v8[nt][r] - mu[r]) * rs[r] * gg + bb;
            srcv[nt][r] = sv;
            sQ[(m0 + lk * 4 + r) * 136 + col] = f2bf(sv);
        }
    }
    __syncthreads();   // B5: W1p0 staged; src ready; sK/sVt dead (sF1 overlays)

    bf16x8 aS[4];
#pragma unroll
    for (int ks = 0; ks < 4; ++ks)
        aS[ks] = *(const bf16x8*)(sQ + (m0 + lr) * 136 + ks * 32 + lk * 8);

    // ---- FFN1 panel0 (W1p0 in sW0; stage W1p1 overlapped) ------------------
    stage_w(W1, 256, 128, 0, sW1, tid);
    {
        f32x4 f1a[8] = {};
#pragma unroll
        for (int ks = 0; ks < 4; ++ks)
#pragma unroll
            for (int nt = 0; nt < 8; ++nt) {
                bf16x8 b = *(const bf16x8*)(sW0 + (nt * 16 + lr) * 136 + ks * 32 + lk * 8);
                f1a[nt] = MFMA16(aS[ks], b, f1a[nt]);
            }
#pragma unroll
        for (int nt = 0; nt < 8; ++nt) {
            int col = nt * 16 + lr; float bb = b1[col];
#pragma unroll
            for (int r = 0; r < 4; ++r)
                sF1[(m0 + lk * 4 + r) * 264 + col] = f2bf(fmaxf(f1a[nt][r] + bb, 0.f));
        }
    }
    __syncthreads();   // B6: W1p1 ready

    // ---- FFN1 panel1 (W1p1 in sW1; stage W2p0 overlapped) ------------------
    stage_w(W2, 128, 0, 0, sW0, tid);
    {
        f32x4 f1a[8] = {};
#pragma unroll
        for (int ks = 0; ks < 4; ++ks)
#pragma unroll
            for (int nt = 0; nt < 8; ++nt) {
                bf16x8 b = *(const bf16x8*)(sW1 + (nt * 16 + lr) * 136 + ks * 32 + lk * 8);
                f1a[nt] = MFMA16(aS[ks], b, f1a[nt]);
            }
#pragma unroll
        for (int nt = 0; nt < 8; ++nt) {
            int col = 128 + nt * 16 + lr; float bb = b1[col];
#pragma unroll
            for (int r = 0; r < 4; ++r)
                sF1[(m0 + lk * 4 + r) * 264 + col] = f2bf(fmaxf(f1a[nt][r] + bb, 0.f));
        }
    }
    __syncthreads();   // B7: W2p0 ready; F1 complete

    // ---- FFN2 panel0 (W2p0 in sW0; stage W2p1 overlapped) ------------------
    f32x4 oa[8] = {};
    stage_w(W2, 128, 0, 128, sW1, tid);
#pragma unroll
    for (int ks = 0; ks < 4; ++ks) {
        bf16x8 aF = *(const bf16x8*)(sF1 + (m0 + lr) * 264 + ks * 32 + lk * 8);
#pragma unroll
        for (int nt = 0; nt < 8; ++nt) {
            bf16x8 b = *(const bf16x8*)(sW0 + (nt * 16 + lr) * 136 + ks * 32 + lk * 8);
            oa[nt] = MFMA16(aF, b, oa[nt]);
        }
    }
    __syncthreads();   // B8: W2p1 ready

    // ---- FFN2 panel1 + residual(src) + LN2 -> out ---------------------------
#pragma unroll
    for (int ks = 0; ks < 4; ++ks) {
        bf16x8 aF = *(const bf16x8*)(sF1 + (m0 + lr) * 264 + 128 + ks * 32 + lk * 8);
#pragma unroll
        for (int nt = 0; nt < 8; ++nt) {
            bf16x8 b = *(const bf16x8*)(sW1 + (nt * 16 + lr) * 136 + ks * 32 + lk * 8);
            oa[nt] = MFMA16(aF, b, oa[nt]);
        }
    }
#pragma unroll
    for (int nt = 0; nt < 8; ++nt) {
        int col = nt * 16 + lr; float bb = b2[col];
#pragma unroll
        for (int r = 0; r < 4; ++r)
            v8[nt][r] = oa[nt][r] + bb + srcv[nt][r];
    }
    row_ln(v8, mu, rs);
    float* ow = out + (size_t)w * 8192;
#pragma unroll
    for (int nt = 0; nt < 8; ++nt) {
        int col = nt * 16 + lr;
        float gg = g2[col], bb = be2[col];
#pragma unroll
        for (int r = 0; r < 4; ++r)
            ow[(m0 + lk * 4 + r) * 128 + col] = (v8[nt][r] - mu[r]) * rs[r] * gg + bb;
    }
}

extern "C" void kernel_launch(void* const* d_in, const int* in_sizes, int n_in,
                              void* d_out, int out_size, void* d_ws, size_t ws_size,
                              hipStream_t stream) {
    (void)in_sizes; (void)n_in; (void)out_size; (void)d_ws; (void)ws_size;
    const float* feat = (const float*)d_in[0];
    const float* pos  = (const float*)d_in[1];
    const unsigned char* mask = (const unsigned char*)d_in[2];
    const float* Wq = (const float*)d_in[3];  const float* bq = (const float*)d_in[4];
    const float* Wk = (const float*)d_in[5];  const float* bk = (const float*)d_in[6];
    const float* Wv = (const float*)d_in[7];  const float* bv = (const float*)d_in[8];
    const float* Wo = (const float*)d_in[9];  const float* bo = (const float*)d_in[10];
    const float* W1 = (const float*)d_in[11]; const float* b1 = (const float*)d_in[12];
    const float* W2 = (const float*)d_in[13]; const float* b2 = (const float*)d_in[14];
    const float* g1 = (const float*)d_in[15]; const float* be1 = (const float*)d_in[16];
    const float* g2 = (const float*)d_in[17]; const float* be2 = (const float*)d_in[18];

    enc_main<<<4096, 256, 0, stream>>>(feat, pos, mask,
                                       Wq, bq, Wk, bk, Wv, bv, Wo, bo,
                                       W1, b1, W2, b2, g1, be1, g2, be2,
                                       (float*)d_out);
}

// Round 11
// 500.349 us; speedup vs baseline: 31.6912x; 1.0659x over previous
//
#include <hip/hip_runtime.h>

typedef __attribute__((ext_vector_type(8))) short bf16x8;
typedef __attribute__((ext_vector_type(4))) float f32x4;
typedef unsigned short u16;
typedef unsigned int u32;

#define MFMA16(a, b, c) __builtin_amdgcn_mfma_f32_16x16x32_bf16((a), (b), (c), 0, 0, 0)
#define CFENCE() asm volatile("" ::: "memory")

// ROUND-11 BISECT: byte-identical to round 10 EXCEPT smem padded 79872 ->
// 98304 to force 1 block/CU. Isolates {R10 staging logic} from {2 blocks/CU}.
// All passes so far were 1 blk/CU (R5/R6/R7); all failures 2 blk/CU (R8/R9/R10).

__device__ __forceinline__ u16 f2bf(float f) {
    union { float f; u32 u; } c; c.f = f;
    u32 r = c.u + 0x7fffu + ((c.u >> 16) & 1u);   // RNE
    return (u16)(r >> 16);
}

// pack 8 f32 -> bf16x8 via HW v_cvt_pk_bf16_f32 (RNE)
__device__ __forceinline__ bf16x8 pack8(f32x4 a, f32x4 b) {
    union { u32 w[4]; bf16x8 v; } r;
    asm("v_cvt_pk_bf16_f32 %0, %1, %2" : "=v"(r.w[0]) : "v"(a[0]), "v"(a[1]));
    asm("v_cvt_pk_bf16_f32 %0, %1, %2" : "=v"(r.w[1]) : "v"(a[2]), "v"(a[3]));
    asm("v_cvt_pk_bf16_f32 %0, %1, %2" : "=v"(r.w[2]) : "v"(b[0]), "v"(b[1]));
    asm("v_cvt_pk_bf16_f32 %0, %1, %2" : "=v"(r.w[3]) : "v"(b[2]), "v"(b[3]));
    return r.v;
}

// stage a [64 n][128 k] transposed bf16 half-panel, row stride 136:
// sW[n][k] = W[k0+k][n0+n]. 2048 quads / 256 thr = 8 per thread.
__device__ __forceinline__ void stage_h(const float* __restrict__ W, int ld,
                                        int n0, int k0, u16* __restrict__ sW,
                                        int t) {
#pragma unroll
    for (int i = 0; i < 8; ++i) {
        int e = i * 256 + t;                      // 0..2047
        int n = e & 63, kq = e >> 6;              // n 0..63, kq 0..31
        const float* src = W + (size_t)(k0 + kq * 4) * ld + n0 + n;
        float a = src[0], b = src[ld], c = src[2 * ld], d = src[3 * ld];
        u32 lo, hi;
        asm("v_cvt_pk_bf16_f32 %0, %1, %2" : "=v"(lo) : "v"(a), "v"(b));
        asm("v_cvt_pk_bf16_f32 %0, %1, %2" : "=v"(hi) : "v"(c), "v"(d));
        uint2 pk; pk.x = lo; pk.y = hi;
        *(uint2*)(sW + n * 136 + kq * 4) = pk;    // 8B-aligned
    }
}

// half of a GEMM: 4 col-tiles x 4 k-steps = 16 MFMA against the staged panel
__device__ __forceinline__ void gemm_h(const bf16x8 aF[4], const u16* __restrict__ sW,
                                       int lr, int lk, f32x4 acc[4]) {
#pragma unroll
    for (int ks = 0; ks < 4; ++ks)
#pragma unroll
        for (int nt = 0; nt < 4; ++nt) {
            bf16x8 b = *(const bf16x8*)(sW + (nt * 16 + lr) * 136 + ks * 32 + lk * 8);
            acc[nt] = MFMA16(aF[ks], b, acc[nt]);
        }
}

// MFMA 16x16x32 bf16 (pinned: learn_hip m89/m91/m97): A row=lane&15,
// k=(lane>>4)*8+j; B col=lane&15, same k map; C/D col=lane&15, row=(lane>>4)*4+r.
__device__ __forceinline__ void row_ln(const f32x4 v[8], float mu[4], float rs[4]) {
#pragma unroll
    for (int r = 0; r < 4; ++r) {
        float s = 0.f;
#pragma unroll
        for (int nt = 0; nt < 8; ++nt) s += v[nt][r];
        s += __shfl_xor(s, 1); s += __shfl_xor(s, 2);
        s += __shfl_xor(s, 4); s += __shfl_xor(s, 8);
        float m_ = s * 0.0078125f;
        float q = 0.f;
#pragma unroll
        for (int nt = 0; nt < 8; ++nt) { float d = v[nt][r] - m_; q += d * d; }
        q += __shfl_xor(q, 1); q += __shfl_xor(q, 2);
        q += __shfl_xor(q, 4); q += __shfl_xor(q, 8);
        mu[r] = m_;
        rs[r] = rsqrtf(q * 0.0078125f + 1e-5f);
    }
}

__global__ __launch_bounds__(256) void enc_main(
    const float* __restrict__ feat, const float* __restrict__ pos,
    const unsigned char* __restrict__ maskb,
    const float* __restrict__ Wq, const float* __restrict__ bq,
    const float* __restrict__ Wk, const float* __restrict__ bk,
    const float* __restrict__ Wv, const float* __restrict__ bv,
    const float* __restrict__ Wo, const float* __restrict__ bo,
    const float* __restrict__ W1, const float* __restrict__ b1,
    const float* __restrict__ W2, const float* __restrict__ b2,
    const float* __restrict__ g1, const float* __restrict__ be1,
    const float* __restrict__ g2, const float* __restrict__ be2,
    float* __restrict__ out) {
    // BISECT: 98304 B -> 1 block/CU. Layout identical to R10 (uses first 79872 B).
    __shared__ __align__(16) char smem[98304];
    u16* sQ    = (u16*)smem;                 // [64][136]  Q -> ctx -> src
    u16* sK    = (u16*)(smem + 17408);       // [64][136]
    u16* sVt   = (u16*)(smem + 34816);       // [128][72]  V^T [d][seq]
    u16* sAttn = (u16*)(smem + 53248);       // [64][72]   own region (no overlay)
    u16* sW    = (u16*)(smem + 62464);       // [64][136]  single staged half-panel
    u16* sF1   = (u16*)(smem + 17408);       // [64][264]  overlays sK+sVt (both dead)

    const int w    = blockIdx.x;
    const int tid  = threadIdx.x;
    const int lane = tid & 63;
    const int lr   = lane & 15;
    const int lk   = lane >> 4;
    const int m0   = (tid >> 6) * 16;

    const float* fw = feat + (size_t)w * 8192;
    const float* pw = pos  + (size_t)w * 8192;

    // first staging issued ASAP (hides under mask decode + A-frag loads)
    stage_h(Wq, 128, 0, 0, sW, tid);

    // ---- mask decode inline (probe logic validated R5/R6) ------------------
    int vld;
    {
        unsigned char smp = maskb[lane * 64 + 63];
        int ones = __popcll(__ballot(smp != 0));
        int m = (ones > 32) ? (maskb[(size_t)w * 64 + lane] != 0)
                            : (((const int*)maskb)[(size_t)w * 64 + lane] != 0);
        vld = 64 - __popcll(__ballot(m));
    }

    // ---- A fragments from global: X = feat+pos, Fv = feat ------------------
    bf16x8 aX[4], aFv[4];
#pragma unroll
    for (int ks = 0; ks < 4; ++ks) {
        const float* fp = fw + (m0 + lr) * 128 + ks * 32 + lk * 8;
        const float* pp = pw + (m0 + lr) * 128 + ks * 32 + lk * 8;
        f32x4 f0 = *(const f32x4*)fp;
        f32x4 f1 = *(const f32x4*)(fp + 4);
        f32x4 p0 = *(const f32x4*)pp;
        f32x4 p1 = *(const f32x4*)(pp + 4);
        aFv[ks] = pack8(f0, f1);
        aX[ks]  = pack8(f0 + p0, f1 + p1);
    }
    __syncthreads();                              // Wq half0 ready

    // ---- Q = X@Wq + bq (2 halves, single-buffered) -------------------------
#pragma unroll
    for (int hf = 0; hf < 2; ++hf) {
        f32x4 acc[4] = {};
        gemm_h(aX, sW, lr, lk, acc);
#pragma unroll
        for (int nt = 0; nt < 4; ++nt) {
            int col = hf * 64 + nt * 16 + lr; float bb = bq[col];
#pragma unroll
            for (int r = 0; r < 4; ++r)
                sQ[(m0 + lk * 4 + r) * 136 + col] = f2bf(acc[nt][r] + bb);
        }
        __syncthreads();                          // sW reads complete
        if (hf == 0) stage_h(Wq, 128, 64, 0, sW, tid);
        else         stage_h(Wk, 128, 0, 0, sW, tid);
        __syncthreads();                          // new panel ready
    }
    // ---- K = X@Wk + bk ------------------------------------------------------
#pragma unroll
    for (int hf = 0; hf < 2; ++hf) {
        f32x4 acc[4] = {};
        gemm_h(aX, sW, lr, lk, acc);
#pragma unroll
        for (int nt = 0; nt < 4; ++nt) {
            int col = hf * 64 + nt * 16 + lr; float bb = bk[col];
#pragma unroll
            for (int r = 0; r < 4; ++r)
                sK[(m0 + lk * 4 + r) * 136 + col] = f2bf(acc[nt][r] + bb);
        }
        __syncthreads();
        if (hf == 0) stage_h(Wk, 128, 64, 0, sW, tid);
        else         stage_h(Wv, 128, 0, 0, sW, tid);
        __syncthreads();
    }
    // ---- V = feat@Wv + bv -> sVt[d][seq] ------------------------------------
#pragma unroll
    for (int hf = 0; hf < 2; ++hf) {
        f32x4 acc[4] = {};
        gemm_h(aFv, sW, lr, lk, acc);
#pragma unroll
        for (int nt = 0; nt < 4; ++nt) {
            int dcol = hf * 64 + nt * 16 + lr; float bb = bv[dcol];
            float e0 = acc[nt][0] + bb, e1 = acc[nt][1] + bb;
            float e2 = acc[nt][2] + bb, e3 = acc[nt][3] + bb;
            u32 lo, hi;
            asm("v_cvt_pk_bf16_f32 %0, %1, %2" : "=v"(lo) : "v"(e0), "v"(e1));
            asm("v_cvt_pk_bf16_f32 %0, %1, %2" : "=v"(hi) : "v"(e2), "v"(e3));
            uint2 pk; pk.x = lo; pk.y = hi;
            *(uint2*)(sVt + dcol * 72 + m0 + lk * 4) = pk;    // 4 contig seq
        }
        __syncthreads();                          // sW reads complete
        if (hf == 0) { stage_h(Wv, 128, 64, 0, sW, tid); __syncthreads(); }
        // hf==1: sW free; Wo half0 staged below, overlapping attention
    }

    // ---- MFMA attention (R7-verbatim; stage Wo half0 overlapped) -----------
    // dup trick: both 16-wide K-halves carry head-h data (offset (lk&1)*8),
    // D = 2*S_h -> scale 0.125. Branchless; A/B share the k-slot map.
    stage_h(Wo, 128, 0, 0, sW, tid);              // sW dead during attention
    const int dup = (lk & 1) * 8;
#pragma unroll 1
    for (int h = 0; h < 8; ++h) {
        bf16x8 aQ = *(const bf16x8*)(sQ + (m0 + lr) * 136 + h * 16 + dup);
        f32x4 sc[4];
#pragma unroll
        for (int nt = 0; nt < 4; ++nt) {
            bf16x8 bK = *(const bf16x8*)(sK + (nt * 16 + lr) * 136 + h * 16 + dup);
            f32x4 zz = {0.f, 0.f, 0.f, 0.f};
            sc[nt] = MFMA16(aQ, bK, zz);
        }
#pragma unroll
        for (int nt = 0; nt < 4; ++nt) {
            bool msk = (nt * 16 + lr) >= vld;
#pragma unroll
            for (int r = 0; r < 4; ++r) {
                float v0 = sc[nt][r] * 0.125f;
                sc[nt][r] = msk ? -1e9f : v0;
            }
        }
        float mx[4], sm[4];
#pragma unroll
        for (int r = 0; r < 4; ++r) {
            float m_ = fmaxf(fmaxf(sc[0][r], sc[1][r]), fmaxf(sc[2][r], sc[3][r]));
            m_ = fmaxf(m_, __shfl_xor(m_, 1));
            m_ = fmaxf(m_, __shfl_xor(m_, 2));
            m_ = fmaxf(m_, __shfl_xor(m_, 4));
            m_ = fmaxf(m_, __shfl_xor(m_, 8));
            mx[r] = m_; sm[r] = 0.f;
        }
#pragma unroll
        for (int nt = 0; nt < 4; ++nt)
#pragma unroll
            for (int r = 0; r < 4; ++r) {
                float e = __expf(sc[nt][r] - mx[r]);
                sc[nt][r] = e; sm[r] += e;
            }
#pragma unroll
        for (int r = 0; r < 4; ++r) {
            float s_ = sm[r];
            s_ += __shfl_xor(s_, 1); s_ += __shfl_xor(s_, 2);
            s_ += __shfl_xor(s_, 4); s_ += __shfl_xor(s_, 8);
            sm[r] = 1.f / s_;
        }
#pragma unroll
        for (int nt = 0; nt < 4; ++nt)
#pragma unroll
            for (int r = 0; r < 4; ++r)
                sAttn[(m0 + lk * 4 + r) * 72 + nt * 16 + lr] = f2bf(sc[nt][r] * sm[r]);
        CFENCE();   // P stores -> aP vector loads (wave-local)
        f32x4 cc = {0.f, 0.f, 0.f, 0.f};
#pragma unroll
        for (int ks = 0; ks < 2; ++ks) {
            bf16x8 aP = *(const bf16x8*)(sAttn + (m0 + lr) * 72 + ks * 32 + lk * 8);
            bf16x8 bV = *(const bf16x8*)(sVt + (h * 16 + lr) * 72 + ks * 32 + lk * 8);
            cc = MFMA16(aP, bV, cc);
        }
        // ctx in-place into sQ (head-h Q cols consumed; wave-local rows)
#pragma unroll
        for (int r = 0; r < 4; ++r)
            sQ[(m0 + lk * 4 + r) * 136 + h * 16 + lr] = f2bf(cc[r]);
    }
    CFENCE();            // ctx stores -> aC vector loads (wave-local)
    __syncthreads();     // Wo half0 staged; attention done block-wide

    // ---- O-projection + residual(feat) + LN1 (2 halves) --------------------
    bf16x8 aC[4];
#pragma unroll
    for (int ks = 0; ks < 4; ++ks)
        aC[ks] = *(const bf16x8*)(sQ + (m0 + lr) * 136 + ks * 32 + lk * 8);
    f32x4 v8[8];
#pragma unroll
    for (int hf = 0; hf < 2; ++hf) {
        f32x4 acc[4] = {};
        gemm_h(aC, sW, lr, lk, acc);
#pragma unroll
        for (int nt = 0; nt < 4; ++nt) {
            int col = hf * 64 + nt * 16 + lr; float bb = bo[col];
#pragma unroll
            for (int r = 0; r < 4; ++r)
                v8[hf * 4 + nt][r] = acc[nt][r] + bb + fw[(m0 + lk * 4 + r) * 128 + col];
        }
        __syncthreads();
        if (hf == 0) stage_h(Wo, 128, 64, 0, sW, tid);
        else         stage_h(W1, 256, 0, 0, sW, tid);
        __syncthreads();
    }
    float mu[4], rs[4];
    row_ln(v8, mu, rs);
    f32x4 srcv[8];                           // f32 src for FFN2 residual
#pragma unroll
    for (int nt = 0; nt < 8; ++nt) {
        int col = nt * 16 + lr;
        float gg = g1[col], bb = be1[col];
#pragma unroll
        for (int r = 0; r < 4; ++r) {
            float sv = (v8[nt][r] - mu[r]) * rs[r] * gg + bb;
            srcv[nt][r] = sv;
            sQ[(m0 + lk * 4 + r) * 136 + col] = f2bf(sv);     // wave-local rows
        }
    }
    CFENCE();
    bf16x8 aS[4];
#pragma unroll
    for (int ks = 0; ks < 4; ++ks)
        aS[ks] = *(const bf16x8*)(sQ + (m0 + lr) * 136 + ks * 32 + lk * 8);

    // ---- FFN1: relu(src@W1 + b1) -> sF1 (4 half-panels of W1) --------------
#pragma unroll
    for (int hf = 0; hf < 4; ++hf) {
        f32x4 f1a[4] = {};
        gemm_h(aS, sW, lr, lk, f1a);
#pragma unroll
        for (int nt = 0; nt < 4; ++nt) {
            int col = hf * 64 + nt * 16 + lr; float bb = b1[col];
#pragma unroll
            for (int r = 0; r < 4; ++r)
                sF1[(m0 + lk * 4 + r) * 264 + col] = f2bf(fmaxf(f1a[nt][r] + bb, 0.f));
        }
        __syncthreads();
        if (hf < 3) stage_h(W1, 256, (hf + 1) * 64, 0, sW, tid);
        else        stage_h(W2, 128, 0, 0, sW, tid);
        __syncthreads();
    }

    // ---- FFN2: 4 half-panels (kh,nh) = (0,0),(0,1),(1,0),(1,1) -------------
    f32x4 oa[8] = {};
#pragma unroll
    for (int s = 0; s < 4; ++s) {
        int kh = s >> 1, nh = s & 1;
#pragma unroll
        for (int ks = 0; ks < 4; ++ks) {
            bf16x8 aF = *(const bf16x8*)(sF1 + (m0 + lr) * 264 + kh * 128 + ks * 32 + lk * 8);
#pragma unroll
            for (int nt = 0; nt < 4; ++nt) {
                bf16x8 b = *(const bf16x8*)(sW + (nt * 16 + lr) * 136 + ks * 32 + lk * 8);
                oa[nh * 4 + nt] = MFMA16(aF, b, oa[nh * 4 + nt]);
            }
        }
        if (s < 3) {
            __syncthreads();
            int ns = s + 1, nkh = ns >> 1, nnh = ns & 1;
            stage_h(W2, 128, nnh * 64, nkh * 128, sW, tid);
            __syncthreads();
        }
    }

    // ---- epilogue: bias + residual(src) + LN2 -> out ------------------------
#pragma unroll
    for (int nt = 0; nt < 8; ++nt) {
        int col = nt * 16 + lr; float bb = b2[col];
#pragma unroll
        for (int r = 0; r < 4; ++r)
            v8[nt][r] = oa[nt][r] + bb + srcv[nt][r];
    }
    row_ln(v8, mu, rs);
    float* ow = out + (size_t)w * 8192;
#pragma unroll
    for (int nt = 0; nt < 8; ++nt) {
        int col = nt * 16 + lr;
        float gg = g2[col], bb = be2[col];
#pragma unroll
        for (int r = 0; r < 4; ++r)
            ow[(m0 + lk * 4 + r) * 128 + col] = (v8[nt][r] - mu[r]) * rs[r] * gg + bb;
    }
}

extern "C" void kernel_launch(void* const* d_in, const int* in_sizes, int n_in,
                              void* d_out, int out_size, void* d_ws, size_t ws_size,
                              hipStream_t stream) {
    (void)in_sizes; (void)n_in; (void)out_size; (void)d_ws; (void)ws_size;
    const float* feat = (const float*)d_in[0];
    const float* pos  = (const float*)d_in[1];
    const unsigned char* mask = (const unsigned char*)d_in[2];
    const float* Wq = (const float*)d_in[3];  const float* bq = (const float*)d_in[4];
    const float* Wk = (const float*)d_in[5];  const float* bk = (const float*)d_in[6];
    const float* Wv = (const float*)d_in[7];  const float* bv = (const float*)d_in[8];
    const float* Wo = (const float*)d_in[9];  const float* bo = (const float*)d_in[10];
    const float* W1 = (const float*)d_in[11]; const float* b1 = (const float*)d_in[12];
    const float* W2 = (const float*)d_in[13]; const float* b2 = (const float*)d_in[14];
    const float* g1 = (const float*)d_in[15]; const float* be1 = (const float*)d_in[16];
    const float* g2 = (const float*)d_in[17]; const float* be2 = (const float*)d_in[18];

    enc_main<<<4096, 256, 0, stream>>>(feat, pos, mask,
                                       Wq, bq, Wk, bk, Wv, bv, Wo, bo,
                                       W1, b1, W2, b2, g1, be1, g2, be2,
                                       (float*)d_out);
}

// Round 12
// 350.799 us; speedup vs baseline: 45.2017x; 1.4263x over previous
//
#include <hip/hip_runtime.h>

typedef __attribute__((ext_vector_type(8))) short bf16x8;
typedef __attribute__((ext_vector_type(4))) float f32x4;
typedef unsigned short u16;
typedef unsigned int u32;

#define MFMA16(a, b, c) __builtin_amdgcn_mfma_f32_16x16x32_bf16((a), (b), (c), 0, 0, 0)
#define CFENCE() asm volatile("" ::: "memory")

// Structure: 512 threads = 8 waves; waves 0-3 process window 2*bid, waves 4-7
// window 2*bid+1. Per-window LDS (62464 B each) + ONE shared weight panel.
// 142336 B total -> 1 block/CU (the 2-blocks/CU config is empirically broken
// for this kernel: R8/R9/R10 fail, R11 bisect passes; do NOT go back).
// INVARIANTS: LDS row strides on bf16x8 paths are x8 u16 (136/72/264);
// single-buffered barrier-sequential staging; d_ws untouched.

__device__ __forceinline__ u16 f2bf(float f) {
    union { float f; u32 u; } c; c.f = f;
    u32 r = c.u + 0x7fffu + ((c.u >> 16) & 1u);   // RNE
    return (u16)(r >> 16);
}

__device__ __forceinline__ bf16x8 pack8(f32x4 a, f32x4 b) {
    union { u32 w[4]; bf16x8 v; } r;
    asm("v_cvt_pk_bf16_f32 %0, %1, %2" : "=v"(r.w[0]) : "v"(a[0]), "v"(a[1]));
    asm("v_cvt_pk_bf16_f32 %0, %1, %2" : "=v"(r.w[1]) : "v"(a[2]), "v"(a[3]));
    asm("v_cvt_pk_bf16_f32 %0, %1, %2" : "=v"(r.w[2]) : "v"(b[0]), "v"(b[1]));
    asm("v_cvt_pk_bf16_f32 %0, %1, %2" : "=v"(r.w[3]) : "v"(b[2]), "v"(b[3]));
    return r.v;
}

// stage a [64 n][128 k] transposed bf16 half-panel, row stride 136:
// sW[n][k] = W[k0+k][n0+n]. 2048 quads / 512 thr = 4 per thread.
__device__ __forceinline__ void stage_h(const float* __restrict__ W, int ld,
                                        int n0, int k0, u16* __restrict__ sW,
                                        int t) {
#pragma unroll
    for (int i = 0; i < 4; ++i) {
        int e = i * 512 + t;                      // 0..2047
        int n = e & 63, kq = e >> 6;              // n 0..63, kq 0..31
        const float* src = W + (size_t)(k0 + kq * 4) * ld + n0 + n;
        float a = src[0], b = src[ld], c = src[2 * ld], d = src[3 * ld];
        u32 lo, hi;
        asm("v_cvt_pk_bf16_f32 %0, %1, %2" : "=v"(lo) : "v"(a), "v"(b));
        asm("v_cvt_pk_bf16_f32 %0, %1, %2" : "=v"(hi) : "v"(c), "v"(d));
        uint2 pk; pk.x = lo; pk.y = hi;
        *(uint2*)(sW + n * 136 + kq * 4) = pk;    // 8B-aligned
    }
}

// half of a GEMM: 4 col-tiles x 4 k-steps = 16 MFMA against the staged panel
__device__ __forceinline__ void gemm_h(const bf16x8 aF[4], const u16* __restrict__ sW,
                                       int lr, int lk, f32x4 acc[4]) {
#pragma unroll
    for (int ks = 0; ks < 4; ++ks)
#pragma unroll
        for (int nt = 0; nt < 4; ++nt) {
            bf16x8 b = *(const bf16x8*)(sW + (nt * 16 + lr) * 136 + ks * 32 + lk * 8);
            acc[nt] = MFMA16(aF[ks], b, acc[nt]);
        }
}

// MFMA 16x16x32 bf16 (pinned: learn_hip m89/m91/m97): A row=lane&15,
// k=(lane>>4)*8+j; B col=lane&15, same k map; C/D col=lane&15, row=(lane>>4)*4+r.
__device__ __forceinline__ void row_ln(const f32x4 v[8], float mu[4], float rs[4]) {
#pragma unroll
    for (int r = 0; r < 4; ++r) {
        float s = 0.f;
#pragma unroll
        for (int nt = 0; nt < 8; ++nt) s += v[nt][r];
        s += __shfl_xor(s, 1); s += __shfl_xor(s, 2);
        s += __shfl_xor(s, 4); s += __shfl_xor(s, 8);
        float m_ = s * 0.0078125f;
        float q = 0.f;
#pragma unroll
        for (int nt = 0; nt < 8; ++nt) { float d = v[nt][r] - m_; q += d * d; }
        q += __shfl_xor(q, 1); q += __shfl_xor(q, 2);
        q += __shfl_xor(q, 4); q += __shfl_xor(q, 8);
        mu[r] = m_;
        rs[r] = rsqrtf(q * 0.0078125f + 1e-5f);
    }
}

__global__ __launch_bounds__(512) void enc_main(
    const float* __restrict__ feat, const float* __restrict__ pos,
    const unsigned char* __restrict__ maskb,
    const float* __restrict__ Wq, const float* __restrict__ bq,
    const float* __restrict__ Wk, const float* __restrict__ bk,
    const float* __restrict__ Wv, const float* __restrict__ bv,
    const float* __restrict__ Wo, const float* __restrict__ bo,
    const float* __restrict__ W1, const float* __restrict__ b1,
    const float* __restrict__ W2, const float* __restrict__ b2,
    const float* __restrict__ g1, const float* __restrict__ be1,
    const float* __restrict__ g2, const float* __restrict__ be2,
    float* __restrict__ out) {
    // 2 windows x 62464 B + shared panel 17408 B = 142336 B -> 1 block/CU
    __shared__ __align__(16) char smem[142336];

    const int tid  = threadIdx.x;            // 0..511
    const int lane = tid & 63;
    const int wid  = tid >> 6;                // wave 0..7
    const int ww   = wid >> 2;                // window index within block
    const int m0   = (wid & 3) * 16;          // wave's row base in its window
    const int lr   = lane & 15;
    const int lk   = lane >> 4;
    const int w    = blockIdx.x * 2 + ww;

    char* wb   = smem + ww * 62464;
    u16* sQ    = (u16*)wb;                    // [64][136]  Q -> ctx -> src
    u16* sK    = (u16*)(wb + 17408);          // [64][136]
    u16* sVt   = (u16*)(wb + 34816);          // [128][72]  V^T [d][seq]
    u16* sAttn = (u16*)(wb + 53248);          // [64][72]
    u16* sF1   = (u16*)(wb + 17408);          // [64][264]  overlays sK+sVt
    u16* sW    = (u16*)(smem + 124928);       // [64][136]  SHARED weight panel

    const float* fw = feat + (size_t)w * 8192;
    const float* pw = pos  + (size_t)w * 8192;

    // first staging issued ASAP (hides under mask decode + A-frag loads)
    stage_h(Wq, 128, 0, 0, sW, tid);

    // ---- mask decode, per wave for its window (probe validated R5/R6) ------
    int vld;
    {
        unsigned char smp = maskb[lane * 64 + 63];
        int ones = __popcll(__ballot(smp != 0));
        int m = (ones > 32) ? (maskb[(size_t)w * 64 + lane] != 0)
                            : (((const int*)maskb)[(size_t)w * 64 + lane] != 0);
        vld = 64 - __popcll(__ballot(m));
    }

    // ---- A fragments from global: X = feat+pos, Fv = feat ------------------
    bf16x8 aX[4], aFv[4];
#pragma unroll
    for (int ks = 0; ks < 4; ++ks) {
        const float* fp = fw + (m0 + lr) * 128 + ks * 32 + lk * 8;
        const float* pp = pw + (m0 + lr) * 128 + ks * 32 + lk * 8;
        f32x4 f0 = *(const f32x4*)fp;
        f32x4 f1 = *(const f32x4*)(fp + 4);
        f32x4 p0 = *(const f32x4*)pp;
        f32x4 p1 = *(const f32x4*)(pp + 4);
        aFv[ks] = pack8(f0, f1);
        aX[ks]  = pack8(f0 + p0, f1 + p1);
    }
    __syncthreads();                              // Wq half0 ready

    // ---- Q = X@Wq + bq (2 halves, single-buffered) -------------------------
#pragma unroll
    for (int hf = 0; hf < 2; ++hf) {
        f32x4 acc[4] = {};
        gemm_h(aX, sW, lr, lk, acc);
#pragma unroll
        for (int nt = 0; nt < 4; ++nt) {
            int col = hf * 64 + nt * 16 + lr; float bb = bq[col];
#pragma unroll
            for (int r = 0; r < 4; ++r)
                sQ[(m0 + lk * 4 + r) * 136 + col] = f2bf(acc[nt][r] + bb);
        }
        __syncthreads();                          // sW reads complete
        if (hf == 0) stage_h(Wq, 128, 64, 0, sW, tid);
        else         stage_h(Wk, 128, 0, 0, sW, tid);
        __syncthreads();                          // new panel ready
    }
    // ---- K = X@Wk + bk ------------------------------------------------------
#pragma unroll
    for (int hf = 0; hf < 2; ++hf) {
        f32x4 acc[4] = {};
        gemm_h(aX, sW, lr, lk, acc);
#pragma unroll
        for (int nt = 0; nt < 4; ++nt) {
            int col = hf * 64 + nt * 16 + lr; float bb = bk[col];
#pragma unroll
            for (int r = 0; r < 4; ++r)
                sK[(m0 + lk * 4 + r) * 136 + col] = f2bf(acc[nt][r] + bb);
        }
        __syncthreads();
        if (hf == 0) stage_h(Wk, 128, 64, 0, sW, tid);
        else         stage_h(Wv, 128, 0, 0, sW, tid);
        __syncthreads();
    }
    // ---- V = feat@Wv + bv -> sVt[d][seq] ------------------------------------
#pragma unroll
    for (int hf = 0; hf < 2; ++hf) {
        f32x4 acc[4] = {};
        gemm_h(aFv, sW, lr, lk, acc);
#pragma unroll
        for (int nt = 0; nt < 4; ++nt) {
            int dcol = hf * 64 + nt * 16 + lr; float bb = bv[dcol];
            float e0 = acc[nt][0] + bb, e1 = acc[nt][1] + bb;
            float e2 = acc[nt][2] + bb, e3 = acc[nt][3] + bb;
            u32 lo, hi;
            asm("v_cvt_pk_bf16_f32 %0, %1, %2" : "=v"(lo) : "v"(e0), "v"(e1));
            asm("v_cvt_pk_bf16_f32 %0, %1, %2" : "=v"(hi) : "v"(e2), "v"(e3));
            uint2 pk; pk.x = lo; pk.y = hi;
            *(uint2*)(sVt + dcol * 72 + m0 + lk * 4) = pk;    // 4 contig seq
        }
        __syncthreads();                          // sW reads complete
        if (hf == 0) { stage_h(Wv, 128, 64, 0, sW, tid); __syncthreads(); }
        // hf==1: sW free; Wo half0 staged below, overlapping attention
    }

    // ---- MFMA attention (wave-local; stage Wo half0 overlapped) ------------
    // dup trick: both 16-wide K-halves carry head-h data (offset (lk&1)*8),
    // D = 2*S_h -> scale 0.125. Branchless; A/B share the k-slot map.
    stage_h(Wo, 128, 0, 0, sW, tid);              // sW dead during attention
    const int dup = (lk & 1) * 8;
#pragma unroll 1
    for (int h = 0; h < 8; ++h) {
        bf16x8 aQ = *(const bf16x8*)(sQ + (m0 + lr) * 136 + h * 16 + dup);
        f32x4 sc[4];
#pragma unroll
        for (int nt = 0; nt < 4; ++nt) {
            bf16x8 bK = *(const bf16x8*)(sK + (nt * 16 + lr) * 136 + h * 16 + dup);
            f32x4 zz = {0.f, 0.f, 0.f, 0.f};
            sc[nt] = MFMA16(aQ, bK, zz);
        }
#pragma unroll
        for (int nt = 0; nt < 4; ++nt) {
            bool msk = (nt * 16 + lr) >= vld;
#pragma unroll
            for (int r = 0; r < 4; ++r) {
                float v0 = sc[nt][r] * 0.125f;
                sc[nt][r] = msk ? -1e9f : v0;
            }
        }
        float mx[4], sm[4];
#pragma unroll
        for (int r = 0; r < 4; ++r) {
            float m_ = fmaxf(fmaxf(sc[0][r], sc[1][r]), fmaxf(sc[2][r], sc[3][r]));
            m_ = fmaxf(m_, __shfl_xor(m_, 1));
            m_ = fmaxf(m_, __shfl_xor(m_, 2));
            m_ = fmaxf(m_, __shfl_xor(m_, 4));
            m_ = fmaxf(m_, __shfl_xor(m_, 8));
            mx[r] = m_; sm[r] = 0.f;
        }
#pragma unroll
        for (int nt = 0; nt < 4; ++nt)
#pragma unroll
            for (int r = 0; r < 4; ++r) {
                float e = __expf(sc[nt][r] - mx[r]);
                sc[nt][r] = e; sm[r] += e;
            }
#pragma unroll
        for (int r = 0; r < 4; ++r) {
            float s_ = sm[r];
            s_ += __shfl_xor(s_, 1); s_ += __shfl_xor(s_, 2);
            s_ += __shfl_xor(s_, 4); s_ += __shfl_xor(s_, 8);
            sm[r] = 1.f / s_;
        }
#pragma unroll
        for (int nt = 0; nt < 4; ++nt)
#pragma unroll
            for (int r = 0; r < 4; ++r)
                sAttn[(m0 + lk * 4 + r) * 72 + nt * 16 + lr] = f2bf(sc[nt][r] * sm[r]);
        CFENCE();   // P stores -> aP vector loads (wave-local)
        f32x4 cc = {0.f, 0.f, 0.f, 0.f};
#pragma unroll
        for (int ks = 0; ks < 2; ++ks) {
            bf16x8 aP = *(const bf16x8*)(sAttn + (m0 + lr) * 72 + ks * 32 + lk * 8);
            bf16x8 bV = *(const bf16x8*)(sVt + (h * 16 + lr) * 72 + ks * 32 + lk * 8);
            cc = MFMA16(aP, bV, cc);
        }
        // ctx in-place into sQ (head-h Q cols consumed; wave-local rows)
#pragma unroll
        for (int r = 0; r < 4; ++r)
            sQ[(m0 + lk * 4 + r) * 136 + h * 16 + lr] = f2bf(cc[r]);
    }
    CFENCE();            // ctx stores -> aC vector loads (wave-local)
    __syncthreads();     // Wo half0 staged; attention done block-wide

    // ---- O-projection + residual(feat) + LN1 (2 halves) --------------------
    bf16x8 aC[4];
#pragma unroll
    for (int ks = 0; ks < 4; ++ks)
        aC[ks] = *(const bf16x8*)(sQ + (m0 + lr) * 136 + ks * 32 + lk * 8);
    f32x4 v8[8];
#pragma unroll
    for (int hf = 0; hf < 2; ++hf) {
        f32x4 acc[4] = {};
        gemm_h(aC, sW, lr, lk, acc);
#pragma unroll
        for (int nt = 0; nt < 4; ++nt) {
            int col = hf * 64 + nt * 16 + lr; float bb = bo[col];
#pragma unroll
            for (int r = 0; r < 4; ++r)
                v8[hf * 4 + nt][r] = acc[nt][r] + bb + fw[(m0 + lk * 4 + r) * 128 + col];
        }
        __syncthreads();
        if (hf == 0) stage_h(Wo, 128, 64, 0, sW, tid);
        else         stage_h(W1, 256, 0, 0, sW, tid);
        __syncthreads();
    }
    float mu[4], rs[4];
    row_ln(v8, mu, rs);
    f32x4 srcv[8];                           // f32 src for FFN2 residual
#pragma unroll
    for (int nt = 0; nt < 8; ++nt) {
        int col = nt * 16 + lr;
        float gg = g1[col], bb = be1[col];
#pragma unroll
        for (int r = 0; r < 4; ++r) {
            float sv = (v8[nt][r] - mu[r]) * rs[r] * gg + bb;
            srcv[nt][r] = sv;
            sQ[(m0 + lk * 4 + r) * 136 + col] = f2bf(sv);     // wave-local rows
        }
    }
    CFENCE();
    bf16x8 aS[4];
#pragma unroll
    for (int ks = 0; ks < 4; ++ks)
        aS[ks] = *(const bf16x8*)(sQ + (m0 + lr) * 136 + ks * 32 + lk * 8);

    // ---- FFN1: relu(src@W1 + b1) -> sF1 (4 half-panels of W1) --------------
#pragma unroll
    for (int hf = 0; hf < 4; ++hf) {
        f32x4 f1a[4] = {};
        gemm_h(aS, sW, lr, lk, f1a);
#pragma unroll
        for (int nt = 0; nt < 4; ++nt) {
            int col = hf * 64 + nt * 16 + lr; float bb = b1[col];
#pragma unroll
            for (int r = 0; r < 4; ++r)
                sF1[(m0 + lk * 4 + r) * 264 + col] = f2bf(fmaxf(f1a[nt][r] + bb, 0.f));
        }
        __syncthreads();
        if (hf < 3) stage_h(W1, 256, (hf + 1) * 64, 0, sW, tid);
        else        stage_h(W2, 128, 0, 0, sW, tid);
        __syncthreads();
    }

    // ---- FFN2: 4 half-panels (kh,nh) = (0,0),(0,1),(1,0),(1,1) -------------
    f32x4 oa[8] = {};
#pragma unroll
    for (int s = 0; s < 4; ++s) {
        int kh = s >> 1, nh = s & 1;
#pragma unroll
        for (int ks = 0; ks < 4; ++ks) {
            bf16x8 aF = *(const bf16x8*)(sF1 + (m0 + lr) * 264 + kh * 128 + ks * 32 + lk * 8);
#pragma unroll
            for (int nt = 0; nt < 4; ++nt) {
                bf16x8 b = *(const bf16x8*)(sW + (nt * 16 + lr) * 136 + ks * 32 + lk * 8);
                oa[nh * 4 + nt] = MFMA16(aF, b, oa[nh * 4 + nt]);
            }
        }
        if (s < 3) {
            __syncthreads();
            int ns = s + 1, nkh = ns >> 1, nnh = ns & 1;
            stage_h(W2, 128, nnh * 64, nkh * 128, sW, tid);
            __syncthreads();
        }
    }

    // ---- epilogue: bias + residual(src) + LN2 -> out ------------------------
#pragma unroll
    for (int nt = 0; nt < 8; ++nt) {
        int col = nt * 16 + lr; float bb = b2[col];
#pragma unroll
        for (int r = 0; r < 4; ++r)
            v8[nt][r] = oa[nt][r] + bb + srcv[nt][r];
    }
    row_ln(v8, mu, rs);
    float* ow = out + (size_t)w * 8192;
#pragma unroll
    for (int nt = 0; nt < 8; ++nt) {
        int col = nt * 16 + lr;
        float gg = g2[col], bb = be2[col];
#pragma unroll
        for (int r = 0; r < 4; ++r)
            ow[(m0 + lk * 4 + r) * 128 + col] = (v8[nt][r] - mu[r]) * rs[r] * gg + bb;
    }
}

extern "C" void kernel_launch(void* const* d_in, const int* in_sizes, int n_in,
                              void* d_out, int out_size, void* d_ws, size_t ws_size,
                              hipStream_t stream) {
    (void)in_sizes; (void)n_in; (void)out_size; (void)d_ws; (void)ws_size;
    const float* feat = (const float*)d_in[0];
    const float* pos  = (const float*)d_in[1];
    const unsigned char* mask = (const unsigned char*)d_in[2];
    const float* Wq = (const float*)d_in[3];  const float* bq = (const float*)d_in[4];
    const float* Wk = (const float*)d_in[5];  const float* bk = (const float*)d_in[6];
    const float* Wv = (const float*)d_in[7];  const float* bv = (const float*)d_in[8];
    const float* Wo = (const float*)d_in[9];  const float* bo = (const float*)d_in[10];
    const float* W1 = (const float*)d_in[11]; const float* b1 = (const float*)d_in[12];
    const float* W2 = (const float*)d_in[13]; const float* b2 = (const float*)d_in[14];
    const float* g1 = (const float*)d_in[15]; const float* be1 = (const float*)d_in[16];
    const float* g2 = (const float*)d_in[17]; const float* be2 = (const float*)d_in[18];

    enc_main<<<2048, 512, 0, stream>>>(feat, pos, mask,
                                       Wq, bq, Wk, bk, Wv, bv, Wo, bo,
                                       W1, b1, W2, b2, g1, be1, g2, be2,
                                       (float*)d_out);
}

// Round 13
// 347.935 us; speedup vs baseline: 45.5737x; 1.0082x over previous
//
#include <hip/hip_runtime.h>

typedef __attribute__((ext_vector_type(8))) short bf16x8;
typedef __attribute__((ext_vector_type(4))) float f32x4;
typedef unsigned short u16;
typedef unsigned int u32;

#define MFMA16(a, b, c) __builtin_amdgcn_mfma_f32_16x16x32_bf16((a), (b), (c), 0, 0, 0)
#define CFENCE() asm volatile("" ::: "memory")

// Structure: 512 threads = 8 waves; waves 0-3 process window 2*bid, waves 4-7
// window 2*bid+1. Per-window LDS (62464 B each) + ONE shared weight panel.
// 142336 B total -> 1 block/CU (the 2-blocks/CU config is empirically broken
// for this kernel: R8/R9/R10 fail, R11 bisect passes; do NOT go back).
// INVARIANTS: LDS row strides on bf16x8 paths are x8 u16 (136/72/264);
// single-buffered barrier-sequential staging; d_ws untouched.

__device__ __forceinline__ u16 f2bf(float f) {
    union { float f; u32 u; } c; c.f = f;
    u32 r = c.u + 0x7fffu + ((c.u >> 16) & 1u);   // RNE
    return (u16)(r >> 16);
}

__device__ __forceinline__ bf16x8 pack8(f32x4 a, f32x4 b) {
    union { u32 w[4]; bf16x8 v; } r;
    asm("v_cvt_pk_bf16_f32 %0, %1, %2" : "=v"(r.w[0]) : "v"(a[0]), "v"(a[1]));
    asm("v_cvt_pk_bf16_f32 %0, %1, %2" : "=v"(r.w[1]) : "v"(a[2]), "v"(a[3]));
    asm("v_cvt_pk_bf16_f32 %0, %1, %2" : "=v"(r.w[2]) : "v"(b[0]), "v"(b[1]));
    asm("v_cvt_pk_bf16_f32 %0, %1, %2" : "=v"(r.w[3]) : "v"(b[2]), "v"(b[3]));
    return r.v;
}

// stage a [64 n][128 k] transposed bf16 half-panel, row stride 136:
// sW[n][k] = W[k0+k][n0+n]. 2048 quads / 512 thr = 4 per thread.
__device__ __forceinline__ void stage_h(const float* __restrict__ W, int ld,
                                        int n0, int k0, u16* __restrict__ sW,
                                        int t) {
#pragma unroll
    for (int i = 0; i < 4; ++i) {
        int e = i * 512 + t;                      // 0..2047
        int n = e & 63, kq = e >> 6;              // n 0..63, kq 0..31
        const float* src = W + (size_t)(k0 + kq * 4) * ld + n0 + n;
        float a = src[0], b = src[ld], c = src[2 * ld], d = src[3 * ld];
        u32 lo, hi;
        asm("v_cvt_pk_bf16_f32 %0, %1, %2" : "=v"(lo) : "v"(a), "v"(b));
        asm("v_cvt_pk_bf16_f32 %0, %1, %2" : "=v"(hi) : "v"(c), "v"(d));
        uint2 pk; pk.x = lo; pk.y = hi;
        *(uint2*)(sW + n * 136 + kq * 4) = pk;    // 8B-aligned
    }
}

// half of a GEMM: 4 col-tiles x 4 k-steps = 16 MFMA against the staged panel
__device__ __forceinline__ void gemm_h(const bf16x8 aF[4], const u16* __restrict__ sW,
                                       int lr, int lk, f32x4 acc[4]) {
#pragma unroll
    for (int ks = 0; ks < 4; ++ks)
#pragma unroll
        for (int nt = 0; nt < 4; ++nt) {
            bf16x8 b = *(const bf16x8*)(sW + (nt * 16 + lr) * 136 + ks * 32 + lk * 8);
            acc[nt] = MFMA16(aF[ks], b, acc[nt]);
        }
}

// MFMA 16x16x32 bf16 (pinned: learn_hip m89/m91/m97): A row=lane&15,
// k=(lane>>4)*8+j; B col=lane&15, same k map; C/D col=lane&15, row=(lane>>4)*4+r.
__device__ __forceinline__ void row_ln(const f32x4 v[8], float mu[4], float rs[4]) {
#pragma unroll
    for (int r = 0; r < 4; ++r) {
        float s = 0.f;
#pragma unroll
        for (int nt = 0; nt < 8; ++nt) s += v[nt][r];
        s += __shfl_xor(s, 1); s += __shfl_xor(s, 2);
        s += __shfl_xor(s, 4); s += __shfl_xor(s, 8);
        float m_ = s * 0.0078125f;
        float q = 0.f;
#pragma unroll
        for (int nt = 0; nt < 8; ++nt) { float d = v[nt][r] - m_; q += d * d; }
        q += __shfl_xor(q, 1); q += __shfl_xor(q, 2);
        q += __shfl_xor(q, 4); q += __shfl_xor(q, 8);
        mu[r] = m_;
        rs[r] = rsqrtf(q * 0.0078125f + 1e-5f);
    }
}

__global__ __launch_bounds__(512) void enc_main(
    const float* __restrict__ feat, const float* __restrict__ pos,
    const unsigned char* __restrict__ maskb,
    const float* __restrict__ Wq, const float* __restrict__ bq,
    const float* __restrict__ Wk, const float* __restrict__ bk,
    const float* __restrict__ Wv, const float* __restrict__ bv,
    const float* __restrict__ Wo, const float* __restrict__ bo,
    const float* __restrict__ W1, const float* __restrict__ b1,
    const float* __restrict__ W2, const float* __restrict__ b2,
    const float* __restrict__ g1, const float* __restrict__ be1,
    const float* __restrict__ g2, const float* __restrict__ be2,
    float* __restrict__ out) {
    // 2 windows x 62464 B + shared panel 17408 B = 142336 B -> 1 block/CU
    __shared__ __align__(16) char smem[142336];

    const int tid  = threadIdx.x;            // 0..511
    const int lane = tid & 63;
    const int wid  = tid >> 6;                // wave 0..7
    const int ww   = wid >> 2;                // window index within block
    const int m0   = (wid & 3) * 16;          // wave's row base in its window
    const int lr   = lane & 15;
    const int lk   = lane >> 4;
    const int w    = blockIdx.x * 2 + ww;

    char* wb   = smem + ww * 62464;
    u16* sQ    = (u16*)wb;                    // [64][136]  Q -> ctx -> src
    u16* sK    = (u16*)(wb + 17408);          // [64][136]
    u16* sVt   = (u16*)(wb + 34816);          // [128][72]  V^T [d][seq]
    u16* sAttn = (u16*)(wb + 53248);          // [64][72]
    u16* sF1   = (u16*)(wb + 17408);          // [64][264]  overlays sK+sVt
    u16* sW    = (u16*)(smem + 124928);       // [64][136]  SHARED weight panel

    const float* fw = feat + (size_t)w * 8192;
    const float* pw = pos  + (size_t)w * 8192;

    // first staging issued ASAP (hides under mask decode + A-frag loads)
    stage_h(Wq, 128, 0, 0, sW, tid);

    // ---- mask decode, per wave for its window (probe validated R5/R6) ------
    int vld;
    {
        unsigned char smp = maskb[lane * 64 + 63];
        int ones = __popcll(__ballot(smp != 0));
        int m = (ones > 32) ? (maskb[(size_t)w * 64 + lane] != 0)
                            : (((const int*)maskb)[(size_t)w * 64 + lane] != 0);
        vld = 64 - __popcll(__ballot(m));
    }

    // ---- A fragments from global: X = feat+pos, Fv = feat ------------------
    bf16x8 aX[4], aFv[4];
#pragma unroll
    for (int ks = 0; ks < 4; ++ks) {
        const float* fp = fw + (m0 + lr) * 128 + ks * 32 + lk * 8;
        const float* pp = pw + (m0 + lr) * 128 + ks * 32 + lk * 8;
        f32x4 f0 = *(const f32x4*)fp;
        f32x4 f1 = *(const f32x4*)(fp + 4);
        f32x4 p0 = *(const f32x4*)pp;
        f32x4 p1 = *(const f32x4*)(pp + 4);
        aFv[ks] = pack8(f0, f1);
        aX[ks]  = pack8(f0 + p0, f1 + p1);
    }
    __syncthreads();                              // Wq half0 ready

    // ---- Q = X@Wq + bq (2 halves, single-buffered) -------------------------
#pragma unroll
    for (int hf = 0; hf < 2; ++hf) {
        f32x4 acc[4] = {};
        gemm_h(aX, sW, lr, lk, acc);
#pragma unroll
        for (int nt = 0; nt < 4; ++nt) {
            int col = hf * 64 + nt * 16 + lr; float bb = bq[col];
#pragma unroll
            for (int r = 0; r < 4; ++r)
                sQ[(m0 + lk * 4 + r) * 136 + col] = f2bf(acc[nt][r] + bb);
        }
        __syncthreads();                          // sW reads complete
        if (hf == 0) stage_h(Wq, 128, 64, 0, sW, tid);
        else         stage_h(Wk, 128, 0, 0, sW, tid);
        __syncthreads();                          // new panel ready
    }
    // ---- K = X@Wk + bk ------------------------------------------------------
#pragma unroll
    for (int hf = 0; hf < 2; ++hf) {
        f32x4 acc[4] = {};
        gemm_h(aX, sW, lr, lk, acc);
#pragma unroll
        for (int nt = 0; nt < 4; ++nt) {
            int col = hf * 64 + nt * 16 + lr; float bb = bk[col];
#pragma unroll
            for (int r = 0; r < 4; ++r)
                sK[(m0 + lk * 4 + r) * 136 + col] = f2bf(acc[nt][r] + bb);
        }
        __syncthreads();
        if (hf == 0) stage_h(Wk, 128, 64, 0, sW, tid);
        else         stage_h(Wv, 128, 0, 0, sW, tid);
        __syncthreads();
    }
    // ---- V = feat@Wv + bv -> sVt[d][seq] ------------------------------------
#pragma unroll
    for (int hf = 0; hf < 2; ++hf) {
        f32x4 acc[4] = {};
        gemm_h(aFv, sW, lr, lk, acc);
#pragma unroll
        for (int nt = 0; nt < 4; ++nt) {
            int dcol = hf * 64 + nt * 16 + lr; float bb = bv[dcol];
            float e0 = acc[nt][0] + bb, e1 = acc[nt][1] + bb;
            float e2 = acc[nt][2] + bb, e3 = acc[nt][3] + bb;
            u32 lo, hi;
            asm("v_cvt_pk_bf16_f32 %0, %1, %2" : "=v"(lo) : "v"(e0), "v"(e1));
            asm("v_cvt_pk_bf16_f32 %0, %1, %2" : "=v"(hi) : "v"(e2), "v"(e3));
            uint2 pk; pk.x = lo; pk.y = hi;
            *(uint2*)(sVt + dcol * 72 + m0 + lk * 4) = pk;    // 4 contig seq
        }
        __syncthreads();                          // sW reads complete
        if (hf == 0) { stage_h(Wv, 128, 64, 0, sW, tid); __syncthreads(); }
        // hf==1: sW free; Wo half0 staged below, overlapping attention
    }

    // ---- MFMA attention (wave-local; stage Wo half0 overlapped) ------------
    // dup trick: both 16-wide K-halves carry head-h data (offset (lk&1)*8),
    // D = 2*S_h -> scale 0.125. Branchless; A/B share the k-slot map.
    stage_h(Wo, 128, 0, 0, sW, tid);              // sW dead during attention
    const int dup = (lk & 1) * 8;
#pragma unroll 1
    for (int h = 0; h < 8; ++h) {
        bf16x8 aQ = *(const bf16x8*)(sQ + (m0 + lr) * 136 + h * 16 + dup);
        f32x4 sc[4];
#pragma unroll
        for (int nt = 0; nt < 4; ++nt) {
            bf16x8 bK = *(const bf16x8*)(sK + (nt * 16 + lr) * 136 + h * 16 + dup);
            f32x4 zz = {0.f, 0.f, 0.f, 0.f};
            sc[nt] = MFMA16(aQ, bK, zz);
        }
#pragma unroll
        for (int nt = 0; nt < 4; ++nt) {
            bool msk = (nt * 16 + lr) >= vld;
#pragma unroll
            for (int r = 0; r < 4; ++r) {
                float v0 = sc[nt][r] * 0.125f;
                sc[nt][r] = msk ? -1e9f : v0;
            }
        }
        float mx[4], sm[4];
#pragma unroll
        for (int r = 0; r < 4; ++r) {
            float m_ = fmaxf(fmaxf(sc[0][r], sc[1][r]), fmaxf(sc[2][r], sc[3][r]));
            m_ = fmaxf(m_, __shfl_xor(m_, 1));
            m_ = fmaxf(m_, __shfl_xor(m_, 2));
            m_ = fmaxf(m_, __shfl_xor(m_, 4));
            m_ = fmaxf(m_, __shfl_xor(m_, 8));
            mx[r] = m_; sm[r] = 0.f;
        }
#pragma unroll
        for (int nt = 0; nt < 4; ++nt)
#pragma unroll
            for (int r = 0; r < 4; ++r) {
                float e = __expf(sc[nt][r] - mx[r]);
                sc[nt][r] = e; sm[r] += e;
            }
#pragma unroll
        for (int r = 0; r < 4; ++r) {
            float s_ = sm[r];
            s_ += __shfl_xor(s_, 1); s_ += __shfl_xor(s_, 2);
            s_ += __shfl_xor(s_, 4); s_ += __shfl_xor(s_, 8);
            sm[r] = 1.f / s_;
        }
#pragma unroll
        for (int nt = 0; nt < 4; ++nt)
#pragma unroll
            for (int r = 0; r < 4; ++r)
                sAttn[(m0 + lk * 4 + r) * 72 + nt * 16 + lr] = f2bf(sc[nt][r] * sm[r]);
        CFENCE();   // P stores -> aP vector loads (wave-local)
        f32x4 cc = {0.f, 0.f, 0.f, 0.f};
#pragma unroll
        for (int ks = 0; ks < 2; ++ks) {
            bf16x8 aP = *(const bf16x8*)(sAttn + (m0 + lr) * 72 + ks * 32 + lk * 8);
            bf16x8 bV = *(const bf16x8*)(sVt + (h * 16 + lr) * 72 + ks * 32 + lk * 8);
            cc = MFMA16(aP, bV, cc);
        }
        // ctx in-place into sQ (head-h Q cols consumed; wave-local rows)
#pragma unroll
        for (int r = 0; r < 4; ++r)
            sQ[(m0 + lk * 4 + r) * 136 + h * 16 + lr] = f2bf(cc[r]);
    }
    CFENCE();            // ctx stores -> aC vector loads (wave-local)
    __syncthreads();     // Wo half0 staged; attention done block-wide

    // ---- O-projection + residual(feat) + LN1 (2 halves) --------------------
    bf16x8 aC[4];
#pragma unroll
    for (int ks = 0; ks < 4; ++ks)
        aC[ks] = *(const bf16x8*)(sQ + (m0 + lr) * 136 + ks * 32 + lk * 8);
    f32x4 v8[8];
#pragma unroll
    for (int hf = 0; hf < 2; ++hf) {
        f32x4 acc[4] = {};
        gemm_h(aC, sW, lr, lk, acc);
#pragma unroll
        for (int nt = 0; nt < 4; ++nt) {
            int col = hf * 64 + nt * 16 + lr; float bb = bo[col];
#pragma unroll
            for (int r = 0; r < 4; ++r)
                v8[hf * 4 + nt][r] = acc[nt][r] + bb + fw[(m0 + lk * 4 + r) * 128 + col];
        }
        __syncthreads();
        if (hf == 0) stage_h(Wo, 128, 64, 0, sW, tid);
        else         stage_h(W1, 256, 0, 0, sW, tid);
        __syncthreads();
    }
    float mu[4], rs[4];
    row_ln(v8, mu, rs);
    f32x4 srcv[8];                           // f32 src for FFN2 residual
#pragma unroll
    for (int nt = 0; nt < 8; ++nt) {
        int col = nt * 16 + lr;
        float gg = g1[col], bb = be1[col];
#pragma unroll
        for (int r = 0; r < 4; ++r) {
            float sv = (v8[nt][r] - mu[r]) * rs[r] * gg + bb;
            srcv[nt][r] = sv;
            sQ[(m0 + lk * 4 + r) * 136 + col] = f2bf(sv);     // wave-local rows
        }
    }
    CFENCE();
    bf16x8 aS[4];
#pragma unroll
    for (int ks = 0; ks < 4; ++ks)
        aS[ks] = *(const bf16x8*)(sQ + (m0 + lr) * 136 + ks * 32 + lk * 8);

    // ---- FFN1: relu(src@W1 + b1) -> sF1 (4 half-panels of W1) --------------
#pragma unroll
    for (int hf = 0; hf < 4; ++hf) {
        f32x4 f1a[4] = {};
        gemm_h(aS, sW, lr, lk, f1a);
#pragma unroll
        for (int nt = 0; nt < 4; ++nt) {
            int col = hf * 64 + nt * 16 + lr; float bb = b1[col];
#pragma unroll
            for (int r = 0; r < 4; ++r)
                sF1[(m0 + lk * 4 + r) * 264 + col] = f2bf(fmaxf(f1a[nt][r] + bb, 0.f));
        }
        __syncthreads();
        if (hf < 3) stage_h(W1, 256, (hf + 1) * 64, 0, sW, tid);
        else        stage_h(W2, 128, 0, 0, sW, tid);
        __syncthreads();
    }

    // ---- FFN2: 4 half-panels (kh,nh) = (0,0),(0,1),(1,0),(1,1) -------------
    f32x4 oa[8] = {};
#pragma unroll
    for (int s = 0; s < 4; ++s) {
        int kh = s >> 1, nh = s & 1;
#pragma unroll
        for (int ks = 0; ks < 4; ++ks) {
            bf16x8 aF = *(const bf16x8*)(sF1 + (m0 + lr) * 264 + kh * 128 + ks * 32 + lk * 8);
#pragma unroll
            for (int nt = 0; nt < 4; ++nt) {
                bf16x8 b = *(const bf16x8*)(sW + (nt * 16 + lr) * 136 + ks * 32 + lk * 8);
                oa[nh * 4 + nt] = MFMA16(aF, b, oa[nh * 4 + nt]);
            }
        }
        if (s < 3) {
            __syncthreads();
            int ns = s + 1, nkh = ns >> 1, nnh = ns & 1;
            stage_h(W2, 128, nnh * 64, nkh * 128, sW, tid);
            __syncthreads();
        }
    }

    // ---- epilogue: bias + residual(src) + LN2 -> out ------------------------
#pragma unroll
    for (int nt = 0; nt < 8; ++nt) {
        int col = nt * 16 + lr; float bb = b2[col];
#pragma unroll
        for (int r = 0; r < 4; ++r)
            v8[nt][r] = oa[nt][r] + bb + srcv[nt][r];
    }
    row_ln(v8, mu, rs);
    float* ow = out + (size_t)w * 8192;
#pragma unroll
    for (int nt = 0; nt < 8; ++nt) {
        int col = nt * 16 + lr;
        float gg = g2[col], bb = be2[col];
#pragma unroll
        for (int r = 0; r < 4; ++r)
            ow[(m0 + lk * 4 + r) * 128 + col] = (v8[nt][r] - mu[r]) * rs[r] * gg + bb;
    }
}

extern "C" void kernel_launch(void* const* d_in, const int* in_sizes, int n_in,
                              void* d_out, int out_size, void* d_ws, size_t ws_size,
                              hipStream_t stream) {
    (void)in_sizes; (void)n_in; (void)out_size; (void)d_ws; (void)ws_size;
    const float* feat = (const float*)d_in[0];
    const float* pos  = (const float*)d_in[1];
    const unsigned char* mask = (const unsigned char*)d_in[2];
    const float* Wq = (const float*)d_in[3];  const float* bq = (const float*)d_in[4];
    const float* Wk = (const float*)d_in[5];  const float* bk = (const float*)d_in[6];
    const float* Wv = (const float*)d_in[7];  const float* bv = (const float*)d_in[8];
    const float* Wo = (const float*)d_in[9];  const float* bo = (const float*)d_in[10];
    const float* W1 = (const float*)d_in[11]; const float* b1 = (const float*)d_in[12];
    const float* W2 = (const float*)d_in[13]; const float* b2 = (const float*)d_in[14];
    const float* g1 = (const float*)d_in[15]; const float* be1 = (const float*)d_in[16];
    const float* g2 = (const float*)d_in[17]; const float* be2 = (const float*)d_in[18];

    enc_main<<<2048, 512, 0, stream>>>(feat, pos, mask,
                                       Wq, bq, Wk, bk, Wv, bv, Wo, bo,
                                       W1, b1, W2, b2, g1, be1, g2, be2,
                                       (float*)d_out);
}

// Round 15
// 337.085 us; speedup vs baseline: 47.0406x; 1.0322x over previous
//
#include <hip/hip_runtime.h>

typedef __attribute__((ext_vector_type(8))) short bf16x8;
typedef __attribute__((ext_vector_type(4))) float f32x4;
typedef unsigned short u16;
typedef unsigned int u32;

#define MFMA16(a, b, c) __builtin_amdgcn_mfma_f32_16x16x32_bf16((a), (b), (c), 0, 0, 0)
#define CFENCE() asm volatile("" ::: "memory")

// Structure: 512 threads = 8 waves; waves 0-3 -> window 2*bid, waves 4-7 ->
// window 2*bid+1. Per-window LDS (62464 B) + DOUBLE-BUFFERED shared weight
// panels (2 x 17408 B) = 159744 B -> 1 block/CU (2-blocks/CU empirically
// broken: R8/R9/R10 fail, R11 bisect; stay at 1).
// Panel chain (R14 bug was FFN2 parity): Q0:A Q1:B K0:A K1:B V0:A V1:B
// attn:A-held/Wo1->B O0:A O1:B|W1_0->A F0:A F1:B F2:A F3:B|W2_00->A
// S0:A S1:B S2:A S3:B.  Stage always targets the buffer consumed 2 steps
// earlier; every cross-wave RAW/WAR crosses exactly one barrier.
// INVARIANTS: LDS row strides on bf16x8 paths are x8 u16 (136/72/264);
// d_ws untouched.

__device__ __forceinline__ u16 f2bf(float f) {
    union { float f; u32 u; } c; c.f = f;
    u32 r = c.u + 0x7fffu + ((c.u >> 16) & 1u);   // RNE
    return (u16)(r >> 16);
}

__device__ __forceinline__ bf16x8 pack8(f32x4 a, f32x4 b) {
    union { u32 w[4]; bf16x8 v; } r;
    asm("v_cvt_pk_bf16_f32 %0, %1, %2" : "=v"(r.w[0]) : "v"(a[0]), "v"(a[1]));
    asm("v_cvt_pk_bf16_f32 %0, %1, %2" : "=v"(r.w[1]) : "v"(a[2]), "v"(a[3]));
    asm("v_cvt_pk_bf16_f32 %0, %1, %2" : "=v"(r.w[2]) : "v"(b[0]), "v"(b[1]));
    asm("v_cvt_pk_bf16_f32 %0, %1, %2" : "=v"(r.w[3]) : "v"(b[2]), "v"(b[3]));
    return r.v;
}

// stage a [64 n][128 k] transposed bf16 half-panel, row stride 136:
// sW[n][k] = W[k0+k][n0+n]. 2048 quads / 512 thr = 4 per thread.
__device__ __forceinline__ void stage_h(const float* __restrict__ W, int ld,
                                        int n0, int k0, u16* __restrict__ sW,
                                        int t) {
#pragma unroll
    for (int i = 0; i < 4; ++i) {
        int e = i * 512 + t;                      // 0..2047
        int n = e & 63, kq = e >> 6;              // n 0..63, kq 0..31
        const float* src = W + (size_t)(k0 + kq * 4) * ld + n0 + n;
        float a = src[0], b = src[ld], c = src[2 * ld], d = src[3 * ld];
        u32 lo, hi;
        asm("v_cvt_pk_bf16_f32 %0, %1, %2" : "=v"(lo) : "v"(a), "v"(b));
        asm("v_cvt_pk_bf16_f32 %0, %1, %2" : "=v"(hi) : "v"(c), "v"(d));
        uint2 pk; pk.x = lo; pk.y = hi;
        *(uint2*)(sW + n * 136 + kq * 4) = pk;    // 8B-aligned
    }
}

// half of a GEMM: 4 col-tiles x 4 k-steps = 16 MFMA against the staged panel
__device__ __forceinline__ void gemm_h(const bf16x8 aF[4], const u16* __restrict__ sW,
                                       int lr, int lk, f32x4 acc[4]) {
#pragma unroll
    for (int ks = 0; ks < 4; ++ks)
#pragma unroll
        for (int nt = 0; nt < 4; ++nt) {
            bf16x8 b = *(const bf16x8*)(sW + (nt * 16 + lr) * 136 + ks * 32 + lk * 8);
            acc[nt] = MFMA16(aF[ks], b, acc[nt]);
        }
}

// MFMA 16x16x32 bf16 (pinned: learn_hip m89/m91/m97): A row=lane&15,
// k=(lane>>4)*8+j; B col=lane&15, same k map; C/D col=lane&15, row=(lane>>4)*4+r.
__device__ __forceinline__ void row_ln(const f32x4 v[8], float mu[4], float rs[4]) {
#pragma unroll
    for (int r = 0; r < 4; ++r) {
        float s = 0.f;
#pragma unroll
        for (int nt = 0; nt < 8; ++nt) s += v[nt][r];
        s += __shfl_xor(s, 1); s += __shfl_xor(s, 2);
        s += __shfl_xor(s, 4); s += __shfl_xor(s, 8);
        float m_ = s * 0.0078125f;
        float q = 0.f;
#pragma unroll
        for (int nt = 0; nt < 8; ++nt) { float d = v[nt][r] - m_; q += d * d; }
        q += __shfl_xor(q, 1); q += __shfl_xor(q, 2);
        q += __shfl_xor(q, 4); q += __shfl_xor(q, 8);
        mu[r] = m_;
        rs[r] = rsqrtf(q * 0.0078125f + 1e-5f);
    }
}

__global__ __launch_bounds__(512) void enc_main(
    const float* __restrict__ feat, const float* __restrict__ pos,
    const unsigned char* __restrict__ maskb,
    const float* __restrict__ Wq, const float* __restrict__ bq,
    const float* __restrict__ Wk, const float* __restrict__ bk,
    const float* __restrict__ Wv, const float* __restrict__ bv,
    const float* __restrict__ Wo, const float* __restrict__ bo,
    const float* __restrict__ W1, const float* __restrict__ b1,
    const float* __restrict__ W2, const float* __restrict__ b2,
    const float* __restrict__ g1, const float* __restrict__ be1,
    const float* __restrict__ g2, const float* __restrict__ be2,
    float* __restrict__ out) {
    // 2 windows x 62464 + 2 panels x 17408 = 159744 B -> 1 block/CU
    __shared__ __align__(16) char smem[159744];

    const int tid  = threadIdx.x;            // 0..511
    const int lane = tid & 63;
    const int wid  = tid >> 6;                // wave 0..7
    const int ww   = wid >> 2;                // window index within block
    const int m0   = (wid & 3) * 16;          // wave's row base in its window
    const int lr   = lane & 15;
    const int lk   = lane >> 4;
    const int w    = blockIdx.x * 2 + ww;

    char* wb   = smem + ww * 62464;
    u16* sQ    = (u16*)wb;                    // [64][136]  Q -> ctx -> src
    u16* sK    = (u16*)(wb + 17408);          // [64][136]
    u16* sVt   = (u16*)(wb + 34816);          // [128][72]  V^T [d][seq]
    u16* sAttn = (u16*)(wb + 53248);          // [64][72]
    u16* sF1   = (u16*)(wb + 17408);          // [64][264]  overlays sK+sVt
    u16* panA  = (u16*)(smem + 124928);       // [64][136]  shared panel A
    u16* panB  = (u16*)(smem + 142336);       // [64][136]  shared panel B

    const float* fw = feat + (size_t)w * 8192;
    const float* pw = pos  + (size_t)w * 8192;

    // P0 = Wq half0 -> A (hides under mask decode + A-frag loads)
    stage_h(Wq, 128, 0, 0, panA, tid);

    // ---- mask decode, per wave for its window (probe validated R5/R6) ------
    int vld;
    {
        unsigned char smp = maskb[lane * 64 + 63];
        int ones = __popcll(__ballot(smp != 0));
        int m = (ones > 32) ? (maskb[(size_t)w * 64 + lane] != 0)
                            : (((const int*)maskb)[(size_t)w * 64 + lane] != 0);
        vld = 64 - __popcll(__ballot(m));
    }

    // ---- A fragments from global: X = feat+pos, Fv = feat ------------------
    bf16x8 aX[4], aFv[4];
#pragma unroll
    for (int ks = 0; ks < 4; ++ks) {
        const float* fp = fw + (m0 + lr) * 128 + ks * 32 + lk * 8;
        const float* pp = pw + (m0 + lr) * 128 + ks * 32 + lk * 8;
        f32x4 f0 = *(const f32x4*)fp;
        f32x4 f1 = *(const f32x4*)(fp + 4);
        f32x4 p0 = *(const f32x4*)pp;
        f32x4 p1 = *(const f32x4*)(pp + 4);
        aFv[ks] = pack8(f0, f1);
        aX[ks]  = pack8(f0 + p0, f1 + p1);
    }
    __syncthreads();                              // P0 ready

    // ---- Q (2 halves) : consume Pi, stage Pi+1 into other buffer -----------
    {   // Q0: gemm(A)=Wq0, stage Wq1->B
        stage_h(Wq, 128, 64, 0, panB, tid);
        f32x4 acc[4] = {};
        gemm_h(aX, panA, lr, lk, acc);
#pragma unroll
        for (int nt = 0; nt < 4; ++nt) {
            int col = nt * 16 + lr; float bb = bq[col];
#pragma unroll
            for (int r = 0; r < 4; ++r)
                sQ[(m0 + lk * 4 + r) * 136 + col] = f2bf(acc[nt][r] + bb);
        }
        __syncthreads();
    }
    {   // Q1: gemm(B)=Wq1, stage Wk0->A
        stage_h(Wk, 128, 0, 0, panA, tid);
        f32x4 acc[4] = {};
        gemm_h(aX, panB, lr, lk, acc);
#pragma unroll
        for (int nt = 0; nt < 4; ++nt) {
            int col = 64 + nt * 16 + lr; float bb = bq[col];
#pragma unroll
            for (int r = 0; r < 4; ++r)
                sQ[(m0 + lk * 4 + r) * 136 + col] = f2bf(acc[nt][r] + bb);
        }
        __syncthreads();
    }
    {   // K0: gemm(A)=Wk0, stage Wk1->B
        stage_h(Wk, 128, 64, 0, panB, tid);
        f32x4 acc[4] = {};
        gemm_h(aX, panA, lr, lk, acc);
#pragma unroll
        for (int nt = 0; nt < 4; ++nt) {
            int col = nt * 16 + lr; float bb = bk[col];
#pragma unroll
            for (int r = 0; r < 4; ++r)
                sK[(m0 + lk * 4 + r) * 136 + col] = f2bf(acc[nt][r] + bb);
        }
        __syncthreads();
    }
    {   // K1: gemm(B)=Wk1, stage Wv0->A
        stage_h(Wv, 128, 0, 0, panA, tid);
        f32x4 acc[4] = {};
        gemm_h(aX, panB, lr, lk, acc);
#pragma unroll
        for (int nt = 0; nt < 4; ++nt) {
            int col = 64 + nt * 16 + lr; float bb = bk[col];
#pragma unroll
            for (int r = 0; r < 4; ++r)
                sK[(m0 + lk * 4 + r) * 136 + col] = f2bf(acc[nt][r] + bb);
        }
        __syncthreads();
    }
    {   // V0: gemm(A)=Wv0, stage Wv1->B
        stage_h(Wv, 128, 64, 0, panB, tid);
        f32x4 acc[4] = {};
        gemm_h(aFv, panA, lr, lk, acc);
#pragma unroll
        for (int nt = 0; nt < 4; ++nt) {
            int dcol = nt * 16 + lr; float bb = bv[dcol];
            float e0 = acc[nt][0] + bb, e1 = acc[nt][1] + bb;
            float e2 = acc[nt][2] + bb, e3 = acc[nt][3] + bb;
            u32 lo, hi;
            asm("v_cvt_pk_bf16_f32 %0, %1, %2" : "=v"(lo) : "v"(e0), "v"(e1));
            asm("v_cvt_pk_bf16_f32 %0, %1, %2" : "=v"(hi) : "v"(e2), "v"(e3));
            uint2 pk; pk.x = lo; pk.y = hi;
            *(uint2*)(sVt + dcol * 72 + m0 + lk * 4) = pk;
        }
        __syncthreads();
    }
    {   // V1: gemm(B)=Wv1, stage Wo0->A
        stage_h(Wo, 128, 0, 0, panA, tid);
        f32x4 acc[4] = {};
        gemm_h(aFv, panB, lr, lk, acc);
#pragma unroll
        for (int nt = 0; nt < 4; ++nt) {
            int dcol = 64 + nt * 16 + lr; float bb = bv[dcol];
            float e0 = acc[nt][0] + bb, e1 = acc[nt][1] + bb;
            float e2 = acc[nt][2] + bb, e3 = acc[nt][3] + bb;
            u32 lo, hi;
            asm("v_cvt_pk_bf16_f32 %0, %1, %2" : "=v"(lo) : "v"(e0), "v"(e1));
            asm("v_cvt_pk_bf16_f32 %0, %1, %2" : "=v"(hi) : "v"(e2), "v"(e3));
            uint2 pk; pk.x = lo; pk.y = hi;
            *(uint2*)(sVt + dcol * 72 + m0 + lk * 4) = pk;
        }
        __syncthreads();   // K, Vt visible; Wo0(A) staged
    }

    // ---- MFMA attention (wave-local; stage Wo1->B under it) ----------------
    // dup trick: both 16-wide K-halves carry head-h data (offset (lk&1)*8),
    // D = 2*S_h -> scale 0.125. Branchless; A/B share the k-slot map.
    stage_h(Wo, 128, 64, 0, panB, tid);           // B free (Wv1 consumed)
    const int dup = (lk & 1) * 8;
#pragma unroll 1
    for (int h = 0; h < 8; ++h) {
        bf16x8 aQ = *(const bf16x8*)(sQ + (m0 + lr) * 136 + h * 16 + dup);
        f32x4 sc[4];
#pragma unroll
        for (int nt = 0; nt < 4; ++nt) {
            bf16x8 bK = *(const bf16x8*)(sK + (nt * 16 + lr) * 136 + h * 16 + dup);
            f32x4 zz = {0.f, 0.f, 0.f, 0.f};
            sc[nt] = MFMA16(aQ, bK, zz);
        }
#pragma unroll
        for (int nt = 0; nt < 4; ++nt) {
            bool msk = (nt * 16 + lr) >= vld;
#pragma unroll
            for (int r = 0; r < 4; ++r) {
                float v0 = sc[nt][r] * 0.125f;
                sc[nt][r] = msk ? -1e9f : v0;
            }
        }
        float mx[4], sm[4];
#pragma unroll
        for (int r = 0; r < 4; ++r) {
            float m_ = fmaxf(fmaxf(sc[0][r], sc[1][r]), fmaxf(sc[2][r], sc[3][r]));
            m_ = fmaxf(m_, __shfl_xor(m_, 1));
            m_ = fmaxf(m_, __shfl_xor(m_, 2));
            m_ = fmaxf(m_, __shfl_xor(m_, 4));
            m_ = fmaxf(m_, __shfl_xor(m_, 8));
            mx[r] = m_; sm[r] = 0.f;
        }
#pragma unroll
        for (int nt = 0; nt < 4; ++nt)
#pragma unroll
            for (int r = 0; r < 4; ++r) {
                float e = __expf(sc[nt][r] - mx[r]);
                sc[nt][r] = e; sm[r] += e;
            }
#pragma unroll
        for (int r = 0; r < 4; ++r) {
            float s_ = sm[r];
            s_ += __shfl_xor(s_, 1); s_ += __shfl_xor(s_, 2);
            s_ += __shfl_xor(s_, 4); s_ += __shfl_xor(s_, 8);
            sm[r] = 1.f / s_;
        }
#pragma unroll
        for (int nt = 0; nt < 4; ++nt)
#pragma unroll
            for (int r = 0; r < 4; ++r)
                sAttn[(m0 + lk * 4 + r) * 72 + nt * 16 + lr] = f2bf(sc[nt][r] * sm[r]);
        CFENCE();   // P stores -> aP vector loads (wave-local)
        f32x4 cc = {0.f, 0.f, 0.f, 0.f};
#pragma unroll
        for (int ks = 0; ks < 2; ++ks) {
            bf16x8 aP = *(const bf16x8*)(sAttn + (m0 + lr) * 72 + ks * 32 + lk * 8);
            bf16x8 bV = *(const bf16x8*)(sVt + (h * 16 + lr) * 72 + ks * 32 + lk * 8);
            cc = MFMA16(aP, bV, cc);
        }
        // ctx in-place into sQ (head-h Q cols consumed; wave-local rows)
#pragma unroll
        for (int r = 0; r < 4; ++r)
            sQ[(m0 + lk * 4 + r) * 136 + h * 16 + lr] = f2bf(cc[r]);
    }
    CFENCE();            // ctx stores -> aC vector loads (wave-local)
    __syncthreads();     // publish Wo1(B); attention complete block-wide

    // ---- O-projection + residual(feat) + LN1 -------------------------------
    bf16x8 aC[4];
#pragma unroll
    for (int ks = 0; ks < 4; ++ks)
        aC[ks] = *(const bf16x8*)(sQ + (m0 + lr) * 136 + ks * 32 + lk * 8);
    f32x4 v8[8];
    {   // O0: gemm(A)=Wo0, no stage (Wo1 already in B)
        f32x4 acc[4] = {};
        gemm_h(aC, panA, lr, lk, acc);
#pragma unroll
        for (int nt = 0; nt < 4; ++nt) {
            int col = nt * 16 + lr; float bb = bo[col];
#pragma unroll
            for (int r = 0; r < 4; ++r)
                v8[nt][r] = acc[nt][r] + bb + fw[(m0 + lk * 4 + r) * 128 + col];
        }
        __syncthreads();   // A reads done (so O1 may stage into A)
    }
    {   // O1: gemm(B)=Wo1, stage W1_0->A
        stage_h(W1, 256, 0, 0, panA, tid);
        f32x4 acc[4] = {};
        gemm_h(aC, panB, lr, lk, acc);
#pragma unroll
        for (int nt = 0; nt < 4; ++nt) {
            int col = 64 + nt * 16 + lr; float bb = bo[col];
#pragma unroll
            for (int r = 0; r < 4; ++r)
                v8[4 + nt][r] = acc[nt][r] + bb + fw[(m0 + lk * 4 + r) * 128 + col];
        }
        __syncthreads();
    }
    float mu[4], rs[4];
    row_ln(v8, mu, rs);
    f32x4 srcv[8];                           // f32 src for FFN2 residual
#pragma unroll
    for (int nt = 0; nt < 8; ++nt) {
        int col = nt * 16 + lr;
        float gg = g1[col], bb = be1[col];
#pragma unroll
        for (int r = 0; r < 4; ++r) {
            float sv = (v8[nt][r] - mu[r]) * rs[r] * gg + bb;
            srcv[nt][r] = sv;
            sQ[(m0 + lk * 4 + r) * 136 + col] = f2bf(sv);     // wave-local rows
        }
    }
    CFENCE();
    bf16x8 aS[4];
#pragma unroll
    for (int ks = 0; ks < 4; ++ks)
        aS[ks] = *(const bf16x8*)(sQ + (m0 + lr) * 136 + ks * 32 + lk * 8);

    // ---- FFN1: relu(src@W1 + b1) -> sF1 (4 half-panels) --------------------
    // F0..F3 consume A,B,A,B; stage W1_1->B, W1_2->A, W1_3->B, W2_00->A.
#pragma unroll
    for (int hf = 0; hf < 4; ++hf) {
        u16* cur = (hf & 1) ? panB : panA;
        u16* nxt = (hf & 1) ? panA : panB;
        if (hf < 3) stage_h(W1, 256, (hf + 1) * 64, 0, nxt, tid);
        else        stage_h(W2, 128, 0, 0, nxt, tid);
        f32x4 f1a[4] = {};
        gemm_h(aS, cur, lr, lk, f1a);
#pragma unroll
        for (int nt = 0; nt < 4; ++nt) {
            int col = hf * 64 + nt * 16 + lr; float bb = b1[col];
#pragma unroll
            for (int r = 0; r < 4; ++r)
                sF1[(m0 + lk * 4 + r) * 264 + col] = f2bf(fmaxf(f1a[nt][r] + bb, 0.f));
        }
        __syncthreads();
    }

    // ---- FFN2: 4 half-panels (kh,nh) = (0,0),(0,1),(1,0),(1,1) -------------
    // F3 staged W2_00 -> A, so S0..S3 consume A,B,A,B (R14 bug: was B,A,B,A).
    f32x4 oa[8] = {};
#pragma unroll
    for (int s = 0; s < 4; ++s) {
        u16* cur = (s & 1) ? panB : panA;
        u16* nxt = (s & 1) ? panA : panB;
        if (s < 3) {
            int ns = s + 1, nkh = ns >> 1, nnh = ns & 1;
            stage_h(W2, 128, nnh * 64, nkh * 128, nxt, tid);
        }
        int kh = s >> 1, nh = s & 1;
#pragma unroll
        for (int ks = 0; ks < 4; ++ks) {
            bf16x8 aF = *(const bf16x8*)(sF1 + (m0 + lr) * 264 + kh * 128 + ks * 32 + lk * 8);
#pragma unroll
            for (int nt = 0; nt < 4; ++nt) {
                bf16x8 b = *(const bf16x8*)(cur + (nt * 16 + lr) * 136 + ks * 32 + lk * 8);
                oa[nh * 4 + nt] = MFMA16(aF, b, oa[nh * 4 + nt]);
            }
        }
        if (s < 3) __syncthreads();
    }

    // ---- epilogue: bias + residual(src) + LN2 -> out ------------------------
#pragma unroll
    for (int nt = 0; nt < 8; ++nt) {
        int col = nt * 16 + lr; float bb = b2[col];
#pragma unroll
        for (int r = 0; r < 4; ++r)
            v8[nt][r] = oa[nt][r] + bb + srcv[nt][r];
    }
    row_ln(v8, mu, rs);
    float* ow = out + (size_t)w * 8192;
#pragma unroll
    for (int nt = 0; nt < 8; ++nt) {
        int col = nt * 16 + lr;
        float gg = g2[col], bb = be2[col];
#pragma unroll
        for (int r = 0; r < 4; ++r)
            ow[(m0 + lk * 4 + r) * 128 + col] = (v8[nt][r] - mu[r]) * rs[r] * gg + bb;
    }
}

extern "C" void kernel_launch(void* const* d_in, const int* in_sizes, int n_in,
                              void* d_out, int out_size, void* d_ws, size_t ws_size,
                              hipStream_t stream) {
    (void)in_sizes; (void)n_in; (void)out_size; (void)d_ws; (void)ws_size;
    const float* feat = (const float*)d_in[0];
    const float* pos  = (const float*)d_in[1];
    const unsigned char* mask = (const unsigned char*)d_in[2];
    const float* Wq = (const float*)d_in[3];  const float* bq = (const float*)d_in[4];
    const float* Wk = (const float*)d_in[5];  const float* bk = (const float*)d_in[6];
    const float* Wv = (const float*)d_in[7];  const float* bv = (const float*)d_in[8];
    const float* Wo = (const float*)d_in[9];  const float* bo = (const float*)d_in[10];
    const float* W1 = (const float*)d_in[11]; const float* b1 = (const float*)d_in[12];
    const float* W2 = (const float*)d_in[13]; const float* b2 = (const float*)d_in[14];
    const float* g1 = (const float*)d_in[15]; const float* be1 = (const float*)d_in[16];
    const float* g2 = (const float*)d_in[17]; const float* be2 = (const float*)d_in[18];

    enc_main<<<2048, 512, 0, stream>>>(feat, pos, mask,
                                       Wq, bq, Wk, bk, Wv, bv, Wo, bo,
                                       W1, b1, W2, b2, g1, be1, g2, be2,
                                       (float*)d_out);
}